// Round 1
// baseline (8496.804 us; speedup 1.0000x reference)
//
#include <hip/hip_runtime.h>

// Problem constants (from reference setup_inputs)
constexpr int Nn  = 50000;   // nodes
constexpr int Ne  = 200000;  // edges
constexpr int Bg  = 64;      // graphs
constexpr int DN  = 128;     // d_node
constexpr int DE  = 64;      // d_edge
constexpr int HD  = 64;      // hidden
constexpr int INN = 64;      // in_node
constexpr int INE = 16;      // in_edge
constexpr int LAY = 6;

// ---------------------------------------------------------------------------
// Encoders
// ---------------------------------------------------------------------------
__global__ __launch_bounds__(128) void enc_node(const float* __restrict__ x,
                                                const float* __restrict__ w,
                                                const float* __restrict__ b,
                                                float* __restrict__ h) {
  __shared__ float xs[INN];
  const int i = blockIdx.x;
  const int t = threadIdx.x;  // out feature 0..127
  if (t < INN) xs[t] = x[(long)i * INN + t];
  __syncthreads();
  float acc = b[t];
  for (int k = 0; k < INN; ++k) acc += xs[k] * w[k * DN + t];
  h[(long)i * DN + t] = acc;
}

__global__ __launch_bounds__(256) void enc_edge(const float* __restrict__ ea,
                                                const float* __restrict__ w,
                                                const float* __restrict__ b,
                                                float* __restrict__ e) {
  const int j = blockIdx.x * 4 + (threadIdx.x >> 6);
  const int c = threadIdx.x & 63;
  if (j >= Ne) return;
  const float* row = ea + (long)j * INE;
  float acc = b[c];
  for (int k = 0; k < INE; ++k) acc += row[k] * w[k * DE + c];
  e[(long)j * DE + c] = acc;
}

// ---------------------------------------------------------------------------
// Degree
// ---------------------------------------------------------------------------
__global__ void deg_count(const int* __restrict__ dst, float* __restrict__ deg) {
  const int j = blockIdx.x * blockDim.x + threadIdx.x;
  if (j < Ne) atomicAdd(&deg[dst[j]], 1.0f);
}

__global__ void deg_inv(float* __restrict__ deg) {
  const int i = blockIdx.x * blockDim.x + threadIdx.x;
  if (i < Nn) deg[i] = 1.0f / fmaxf(deg[i], 1.0f);
}

// ---------------------------------------------------------------------------
// Edge layer: e' = e + MLP([hs, hd, e + hs@mw]); scatter-add e' into m[dst]
// One wave handles EPW=4 edges; LDS holds activations [k][edge] so a single
// broadcast ds_read_b128 feeds 4 fmacs per weight element.
// ---------------------------------------------------------------------------
constexpr int WPB = 4;  // waves per block
constexpr int EPW = 4;  // edges per wave

__global__ __launch_bounds__(256) void edge_layer(
    const float* __restrict__ h, float* __restrict__ e, float* __restrict__ m,
    const int* __restrict__ src, const int* __restrict__ dst,
    const float* __restrict__ mw,   // [128,64]
    const float* __restrict__ ew1,  // [320,64]
    const float* __restrict__ eb1,  // [64]
    const float* __restrict__ ew2,  // [64,64]
    const float* __restrict__ eb2)  // [64]
{
  // per wave: 384 rows (hs 0..127 | hd 128..255 | t 256..319 | u 320..383) x 4 edges
  __shared__ float lds[WPB][384][EPW];
  const int lane = threadIdx.x & 63;
  const int wv   = threadIdx.x >> 6;
  const int gw   = blockIdx.x * WPB + wv;
  const int nw   = gridDim.x * WPB;
  const int ngroups = Ne / EPW;  // 50000 (divides evenly)
  const int iters = (ngroups + nw - 1) / nw;  // uniform across grid -> barrier-safe

  float (*buf)[EPW] = lds[wv];

  for (int it = 0; it < iters; ++it) {
    const int g = gw + it * nw;
    const bool act = g < ngroups;
    const int j0 = g * EPW;
    float ej[EPW];
    int dn[EPW];

    if (act) {
#pragma unroll
      for (int p = 0; p < EPW; ++p) {
        const int j = j0 + p;
        const int s = src[j];
        dn[p] = dst[j];
        const float* hs = h + (long)s * DN;
        const float* hd = h + (long)dn[p] * DN;
        buf[lane][p]        = hs[lane];
        buf[64 + lane][p]   = hs[64 + lane];
        buf[128 + lane][p]  = hd[lane];
        buf[192 + lane][p]  = hd[64 + lane];
        ej[p] = e[(long)j * DE + lane];
      }
    }
    __syncthreads();

    // t = e + hs @ mw
    if (act) {
      float acc[EPW];
#pragma unroll
      for (int p = 0; p < EPW; ++p) acc[p] = ej[p];
      for (int k = 0; k < DN; ++k) {
        const float wk = mw[k * DE + lane];
        const float4 a = *(const float4*)&buf[k][0];
        acc[0] += a.x * wk; acc[1] += a.y * wk;
        acc[2] += a.z * wk; acc[3] += a.w * wk;
      }
#pragma unroll
      for (int p = 0; p < EPW; ++p) buf[256 + lane][p] = acc[p];
    }
    __syncthreads();

    // u = relu([hs,hd,t] @ ew1 + eb1)
    if (act) {
      float acc[EPW];
#pragma unroll
      for (int p = 0; p < EPW; ++p) acc[p] = eb1[lane];
      for (int k = 0; k < 320; ++k) {
        const float wk = ew1[k * HD + lane];
        const float4 a = *(const float4*)&buf[k][0];
        acc[0] += a.x * wk; acc[1] += a.y * wk;
        acc[2] += a.z * wk; acc[3] += a.w * wk;
      }
#pragma unroll
      for (int p = 0; p < EPW; ++p) buf[320 + lane][p] = fmaxf(acc[p], 0.0f);
    }
    __syncthreads();

    // e' = e + u @ ew2 + eb2 ; store + scatter
    if (act) {
      float acc[EPW];
#pragma unroll
      for (int p = 0; p < EPW; ++p) acc[p] = ej[p] + eb2[lane];
      for (int k = 0; k < HD; ++k) {
        const float wk = ew2[k * DE + lane];
        const float4 a = *(const float4*)&buf[320 + k][0];
        acc[0] += a.x * wk; acc[1] += a.y * wk;
        acc[2] += a.z * wk; acc[3] += a.w * wk;
      }
#pragma unroll
      for (int p = 0; p < EPW; ++p) {
        e[(long)(j0 + p) * DE + lane] = acc[p];
        atomicAdd(&m[(long)dn[p] * DE + lane], acc[p]);
      }
    }
    __syncthreads();
  }
}

// ---------------------------------------------------------------------------
// Node layer: h' = h + MLP([h, m*invdeg])
// ---------------------------------------------------------------------------
constexpr int NPW = 4;  // nodes per wave

__global__ __launch_bounds__(256) void node_layer(
    float* __restrict__ h, const float* __restrict__ m,
    const float* __restrict__ invdeg,
    const float* __restrict__ vw1,  // [192,64]
    const float* __restrict__ vb1,  // [64]
    const float* __restrict__ vw2,  // [64,128]
    const float* __restrict__ vb2)  // [128]
{
  // per wave: 256 rows (h 0..127 | md 128..191 | u 192..255) x 4 nodes
  __shared__ float lds[WPB][256][NPW];
  const int lane = threadIdx.x & 63;
  const int wv   = threadIdx.x >> 6;
  const int gw   = blockIdx.x * WPB + wv;
  const int nw   = gridDim.x * WPB;
  const int ngroups = Nn / NPW;  // 12500
  const int iters = (ngroups + nw - 1) / nw;

  float (*buf)[NPW] = lds[wv];

  for (int it = 0; it < iters; ++it) {
    const int g = gw + it * nw;
    const bool act = g < ngroups;
    const int i0 = g * NPW;
    float hv0[NPW], hv1[NPW];

    if (act) {
#pragma unroll
      for (int p = 0; p < NPW; ++p) {
        const int i = i0 + p;
        hv0[p] = h[(long)i * DN + lane];
        hv1[p] = h[(long)i * DN + 64 + lane];
        buf[lane][p]      = hv0[p];
        buf[64 + lane][p] = hv1[p];
        buf[128 + lane][p] = m[(long)i * DE + lane] * invdeg[i];
      }
    }
    __syncthreads();

    // u = relu([h, md] @ vw1 + vb1)
    if (act) {
      float acc[NPW];
#pragma unroll
      for (int p = 0; p < NPW; ++p) acc[p] = vb1[lane];
      for (int k = 0; k < 192; ++k) {
        const float wk = vw1[k * HD + lane];
        const float4 a = *(const float4*)&buf[k][0];
        acc[0] += a.x * wk; acc[1] += a.y * wk;
        acc[2] += a.z * wk; acc[3] += a.w * wk;
      }
#pragma unroll
      for (int p = 0; p < NPW; ++p) buf[192 + lane][p] = fmaxf(acc[p], 0.0f);
    }
    __syncthreads();

    // h += u @ vw2 + vb2  (each lane does channels lane and lane+64)
    if (act) {
      float accA[NPW], accB[NPW];
#pragma unroll
      for (int p = 0; p < NPW; ++p) { accA[p] = vb2[lane]; accB[p] = vb2[64 + lane]; }
      for (int k = 0; k < HD; ++k) {
        const float wA = vw2[k * DN + lane];
        const float wB = vw2[k * DN + 64 + lane];
        const float4 a = *(const float4*)&buf[192 + k][0];
        accA[0] += a.x * wA; accA[1] += a.y * wA;
        accA[2] += a.z * wA; accA[3] += a.w * wA;
        accB[0] += a.x * wB; accB[1] += a.y * wB;
        accB[2] += a.z * wB; accB[3] += a.w * wB;
      }
#pragma unroll
      for (int p = 0; p < NPW; ++p) {
        const int i = i0 + p;
        h[(long)i * DN + lane]      = hv0[p] + accA[p];
        h[(long)i * DN + 64 + lane] = hv1[p] + accB[p];
      }
    }
    __syncthreads();
  }
}

// ---------------------------------------------------------------------------
// Readout
// ---------------------------------------------------------------------------
__global__ __launch_bounds__(128) void graph_acc(const float* __restrict__ h,
                                                 const int* __restrict__ batch,
                                                 float* __restrict__ gacc,
                                                 float* __restrict__ gcnt) {
  const int i = blockIdx.x;
  const int c = threadIdx.x;
  const int b = batch[i];
  atomicAdd(&gacc[b * DN + c], h[(long)i * DN + c]);
  if (c == 0) atomicAdd(&gcnt[b], 1.0f);
}

__global__ __launch_bounds__(128) void readout(const float* __restrict__ gacc,
                                               const float* __restrict__ gcnt,
                                               const float* __restrict__ w1,
                                               const float* __restrict__ b1,
                                               const float* __restrict__ w2,
                                               const float* __restrict__ b2,
                                               float* __restrict__ out) {
  __shared__ float g[DN], t1[DN];
  const int b = blockIdx.x;
  const int c = threadIdx.x;
  const float inv = 1.0f / fmaxf(gcnt[b], 1.0f);
  g[c] = gacc[b * DN + c] * inv;
  __syncthreads();
  float acc = b1[c];
  for (int k = 0; k < DN; ++k) acc += g[k] * w1[k * DN + c];
  t1[c] = fmaxf(acc, 0.0f);
  __syncthreads();
  acc = b2[c];
  for (int k = 0; k < DN; ++k) acc += t1[k] * w2[k * DN + c];
  out[b * DN + c] = acc;
}

// ---------------------------------------------------------------------------
// Launch
// ---------------------------------------------------------------------------
extern "C" void kernel_launch(void* const* d_in, const int* in_sizes, int n_in,
                              void* d_out, int out_size, void* d_ws, size_t ws_size,
                              hipStream_t stream) {
  const float* x       = (const float*)d_in[0];
  const float* ea      = (const float*)d_in[1];
  const int*   ei      = (const int*)d_in[2];   // [2,E]: row0=src, row1=dst
  const int*   batch   = (const int*)d_in[3];
  const float* lin_x_w = (const float*)d_in[4];
  const float* lin_x_b = (const float*)d_in[5];
  const float* lin_e_w = (const float*)d_in[6];
  const float* lin_e_b = (const float*)d_in[7];
  const float* msg_w   = (const float*)d_in[8];    // [L,128,64]
  const float* phie_w1 = (const float*)d_in[9];    // [L,320,64]
  const float* phie_b1 = (const float*)d_in[10];   // [L,64]
  const float* phie_w2 = (const float*)d_in[11];   // [L,64,64]
  const float* phie_b2 = (const float*)d_in[12];   // [L,64]
  const float* phiv_w1 = (const float*)d_in[13];   // [L,192,64]
  const float* phiv_b1 = (const float*)d_in[14];   // [L,64]
  const float* phiv_w2 = (const float*)d_in[15];   // [L,64,128]
  const float* phiv_b2 = (const float*)d_in[16];   // [L,128]
  const float* ro_w1   = (const float*)d_in[17];
  const float* ro_b1   = (const float*)d_in[18];
  const float* ro_w2   = (const float*)d_in[19];
  const float* ro_b2   = (const float*)d_in[20];

  const int* srcp = ei;
  const int* dstp = ei + Ne;

  float* h    = (float*)d_ws;            // N*128
  float* e    = h + (long)Nn * DN;       // E*64
  float* m    = e + (long)Ne * DE;       // N*64
  float* degv = m + (long)Nn * DE;       // N
  float* gacc = degv + Nn;               // B*128
  float* gcnt = gacc + Bg * DN;          // B

  // zero what must be zero (ws is poisoned before every call)
  hipMemsetAsync(degv, 0, sizeof(float) * (Nn + Bg * DN + Bg), stream);

  enc_node<<<Nn, 128, 0, stream>>>(x, lin_x_w, lin_x_b, h);
  enc_edge<<<Ne / 4, 256, 0, stream>>>(ea, lin_e_w, lin_e_b, e);
  deg_count<<<(Ne + 255) / 256, 256, 0, stream>>>(dstp, degv);
  deg_inv<<<(Nn + 255) / 256, 256, 0, stream>>>(degv);

  for (int l = 0; l < LAY; ++l) {
    hipMemsetAsync(m, 0, sizeof(float) * (long)Nn * DE, stream);
    edge_layer<<<2048, 256, 0, stream>>>(
        h, e, m, srcp, dstp,
        msg_w + (long)l * DN * DE,
        phie_w1 + (long)l * (DE + 2 * DN) * HD,
        phie_b1 + (long)l * HD,
        phie_w2 + (long)l * HD * DE,
        phie_b2 + (long)l * DE);
    node_layer<<<1024, 256, 0, stream>>>(
        h, m, degv,
        phiv_w1 + (long)l * (DN + DE) * HD,
        phiv_b1 + (long)l * HD,
        phiv_w2 + (long)l * HD * DN,
        phiv_b2 + (long)l * DN);
  }

  graph_acc<<<Nn, 128, 0, stream>>>(h, batch, gacc, gcnt);
  readout<<<Bg, 128, 0, stream>>>(gacc, gcnt, ro_w1, ro_b1, ro_w2, ro_b2,
                                  (float*)d_out);
}

// Round 2
// 1384.942 us; speedup vs baseline: 6.1351x; 6.1351x over previous
//
#include <hip/hip_runtime.h>

// Problem constants
constexpr int Nn  = 50000;
constexpr int Ne  = 200000;
constexpr int Bg  = 64;
constexpr int DN  = 128;
constexpr int DE  = 64;
constexpr int HD  = 64;
constexpr int INN = 64;
constexpr int INE = 16;
constexpr int LAY = 6;

typedef __attribute__((ext_vector_type(8))) short sh8;  // 8 bf16 = 4 VGPR
typedef __attribute__((ext_vector_type(4))) float f4;   // C/D frag

__device__ inline unsigned short f2bf(float x) {
  union { float f; unsigned u; } v; v.f = x;
  unsigned r = v.u + 0x7FFF + ((v.u >> 16) & 1);  // RNE
  return (unsigned short)(r >> 16);
}

__device__ inline f4 mfma16(sh8 a, sh8 b, f4 c) {
  return __builtin_amdgcn_mfma_f32_16x16x32_bf16(a, b, c, 0, 0, 0);
}

// ---------------------------------------------------------------------------
// Weight prep (runs every launch; trivial cost).
// weT[l][n][k], k in [0,320): fused W1s (k<128), W1d (128..255), W1e (256..319)
// ew2T[l][n][k] k<64 ; vw1T[l][n][k] k<192 ; vw2T[l][n][k] n<128,k<64
// ---------------------------------------------------------------------------
__global__ __launch_bounds__(64) void prep_we(const float* __restrict__ ew1,
                                              const float* __restrict__ mw,
                                              const float* __restrict__ ew2,
                                              unsigned short* __restrict__ weT,
                                              unsigned short* __restrict__ ew2T) {
  const int l = blockIdx.x >> 6, n = blockIdx.x & 63, t = threadIdx.x;
  const float* E1 = ew1 + (long)l * 320 * 64;
  const float* MW = mw + (long)l * 128 * 64;
  const float* E2 = ew2 + (long)l * 64 * 64;
  unsigned short* W = weT + (long)l * 64 * 320 + (long)n * 320;
  __shared__ float c[64];
  c[t] = E1[(256 + t) * 64 + n];
  __syncthreads();
  for (int k = t; k < 128; k += 64) {
    float s = E1[k * 64 + n];
    for (int j = 0; j < 64; ++j) s += MW[k * 64 + j] * c[j];
    W[k] = f2bf(s);
  }
  for (int k = 128 + t; k < 320; k += 64) W[k] = f2bf(E1[k * 64 + n]);
  ew2T[(long)l * 64 * 64 + n * 64 + t] = f2bf(E2[t * 64 + n]);
}

__global__ __launch_bounds__(64) void prep_wv(const float* __restrict__ vw1,
                                              const float* __restrict__ vw2,
                                              unsigned short* __restrict__ vw1T,
                                              unsigned short* __restrict__ vw2T) {
  const int l = blockIdx.x >> 7, n = blockIdx.x & 127, t = threadIdx.x;
  vw2T[(long)l * 128 * 64 + n * 64 + t] = f2bf(vw2[(long)l * 64 * 128 + t * 128 + n]);
  if (n < 64) {
    for (int k = t; k < 192; k += 64)
      vw1T[(long)l * 64 * 192 + n * 192 + k] = f2bf(vw1[(long)l * 192 * 64 + k * 64 + n]);
  }
}

// ---------------------------------------------------------------------------
// Encoders (fp32 math, also write bf16 mirrors)
// ---------------------------------------------------------------------------
__global__ __launch_bounds__(128) void enc_node(const float* __restrict__ x,
                                                const float* __restrict__ w,
                                                const float* __restrict__ b,
                                                float* __restrict__ h,
                                                unsigned short* __restrict__ hb) {
  __shared__ float xs[INN];
  const int i = blockIdx.x, t = threadIdx.x;
  if (t < INN) xs[t] = x[(long)i * INN + t];
  __syncthreads();
  float acc = b[t];
  for (int k = 0; k < INN; ++k) acc += xs[k] * w[k * DN + t];
  h[(long)i * DN + t] = acc;
  hb[(long)i * DN + t] = f2bf(acc);
}

__global__ __launch_bounds__(256) void enc_edge(const float* __restrict__ ea,
                                                const float* __restrict__ w,
                                                const float* __restrict__ b,
                                                float* __restrict__ e,
                                                unsigned short* __restrict__ eb) {
  const int j = blockIdx.x * 4 + (threadIdx.x >> 6);
  const int c = threadIdx.x & 63;
  if (j >= Ne) return;
  const float* row = ea + (long)j * INE;
  float acc = b[c];
  for (int k = 0; k < INE; ++k) acc += row[k] * w[k * DE + c];
  e[(long)j * DE + c] = acc;
  eb[(long)j * DE + c] = f2bf(acc);
}

__global__ void deg_count(const int* __restrict__ dst, float* __restrict__ deg) {
  const int j = blockIdx.x * blockDim.x + threadIdx.x;
  if (j < Ne) atomicAdd(&deg[dst[j]], 1.0f);
}
__global__ void deg_inv(float* __restrict__ deg) {
  const int i = blockIdx.x * blockDim.x + threadIdx.x;
  if (i < Nn) deg[i] = 1.0f / fmaxf(deg[i], 1.0f);
}

// ---------------------------------------------------------------------------
// Edge layer (MFMA). Wave = 64 edges. A = [hb[src] | hb[dst] | eb] (K=320).
// u = relu(A @ W1 + b1); e' = e + u @ W2 + b2; scatter-add e' into m[dst].
// ---------------------------------------------------------------------------
constexpr int UP = 72;  // Us pitch (bf16 elems): 144B, 16B-aligned, 2-way banks

__global__ __launch_bounds__(256) void edge_layer_mfma(
    const unsigned short* __restrict__ hb,
    float* __restrict__ e, unsigned short* __restrict__ eb,
    float* __restrict__ m,
    const int* __restrict__ src, const int* __restrict__ dst,
    const unsigned short* __restrict__ weT,   // [64][320]
    const unsigned short* __restrict__ ew2T,  // [64][64]
    const float* __restrict__ b1, const float* __restrict__ b2) {
  __shared__ unsigned short Us[4][64 * UP];
  const int lane = threadIdx.x & 63;
  const int wv   = threadIdx.x >> 6;
  const int quad = lane >> 4;
  const int lm   = lane & 15;
  const int wid  = blockIdx.x * 4 + wv;
  const int ntiles = Ne / 64;  // 3125
  const bool act = wid < ntiles;
  const int j0 = wid * 64;
  unsigned short* us = Us[wv];

  if (act) {
    int aoff_s[4], aoff_d[4], aoff_e[4];
#pragma unroll
    for (int mt = 0; mt < 4; ++mt) {
      const int j = j0 + mt * 16 + lm;
      aoff_s[mt] = src[j] * DN;
      aoff_d[mt] = dst[j] * DN;
      aoff_e[mt] = j * DE;
    }
    f4 acc[4][4];
#pragma unroll
    for (int mt = 0; mt < 4; ++mt)
#pragma unroll
      for (int nt = 0; nt < 4; ++nt) acc[mt][nt] = f4{0.f, 0.f, 0.f, 0.f};

#pragma unroll
    for (int ks = 0; ks < 10; ++ks) {
      const int kb = ks * 32 + quad * 8;
      sh8 a[4], b[4];
#pragma unroll
      for (int mt = 0; mt < 4; ++mt) {
        const unsigned short* ap;
        if (ks < 4)      ap = hb + aoff_s[mt] + kb;
        else if (ks < 8) ap = hb + aoff_d[mt] + (kb - 128);
        else             ap = eb + aoff_e[mt] + (kb - 256);
        a[mt] = *(const sh8*)ap;
      }
#pragma unroll
      for (int nt = 0; nt < 4; ++nt)
        b[nt] = *(const sh8*)(weT + (nt * 16 + lm) * 320 + kb);
#pragma unroll
      for (int mt = 0; mt < 4; ++mt)
#pragma unroll
        for (int nt = 0; nt < 4; ++nt)
          acc[mt][nt] = mfma16(a[mt], b[nt], acc[mt][nt]);
    }
    // u epilogue: bias + relu, C-layout -> Us[row][col]
    float b1v[4];
#pragma unroll
    for (int nt = 0; nt < 4; ++nt) b1v[nt] = b1[nt * 16 + lm];
#pragma unroll
    for (int mt = 0; mt < 4; ++mt)
#pragma unroll
      for (int nt = 0; nt < 4; ++nt)
#pragma unroll
        for (int r = 0; r < 4; ++r) {
          const int row = mt * 16 + quad * 4 + r;
          const int col = nt * 16 + lm;
          us[row * UP + col] = f2bf(fmaxf(acc[mt][nt][r] + b1v[nt], 0.f));
        }
  }
  __syncthreads();
  if (act) {
    f4 acc2[4][4];
#pragma unroll
    for (int mt = 0; mt < 4; ++mt)
#pragma unroll
      for (int nt = 0; nt < 4; ++nt) acc2[mt][nt] = f4{0.f, 0.f, 0.f, 0.f};
#pragma unroll
    for (int ks = 0; ks < 2; ++ks) {
      const int kb = ks * 32 + quad * 8;
      sh8 a[4], b[4];
#pragma unroll
      for (int mt = 0; mt < 4; ++mt)
        a[mt] = *(const sh8*)&us[(mt * 16 + lm) * UP + kb];
#pragma unroll
      for (int nt = 0; nt < 4; ++nt)
        b[nt] = *(const sh8*)(ew2T + (nt * 16 + lm) * 64 + kb);
#pragma unroll
      for (int mt = 0; mt < 4; ++mt)
#pragma unroll
        for (int nt = 0; nt < 4; ++nt)
          acc2[mt][nt] = mfma16(a[mt], b[nt], acc2[mt][nt]);
    }
    float b2v[4];
#pragma unroll
    for (int nt = 0; nt < 4; ++nt) b2v[nt] = b2[nt * 16 + lm];
#pragma unroll
    for (int mt = 0; mt < 4; ++mt)
#pragma unroll
      for (int r = 0; r < 4; ++r) {
        const int j = j0 + mt * 16 + quad * 4 + r;
        const int dj = dst[j];
#pragma unroll
        for (int nt = 0; nt < 4; ++nt) {
          const int col = nt * 16 + lm;
          const float out = e[(long)j * DE + col] + acc2[mt][nt][r] + b2v[nt];
          e[(long)j * DE + col] = out;
          eb[(long)j * DE + col] = f2bf(out);
          atomicAdd(&m[(long)dj * DE + col], out);
        }
      }
  }
}

// ---------------------------------------------------------------------------
// mb = bf16(m * invdeg)
// ---------------------------------------------------------------------------
__global__ void node_prep(const float* __restrict__ m,
                          const float* __restrict__ invdeg,
                          unsigned short* __restrict__ mb) {
  const long i = (long)blockIdx.x * blockDim.x + threadIdx.x;
  if (i < (long)Nn * DE) mb[i] = f2bf(m[i] * invdeg[i >> 6]);
}

// ---------------------------------------------------------------------------
// Node layer (MFMA). Wave = 64 nodes. A = [hb | mb] (K=192).
// u = relu(A @ vw1 + b1); h' = h + u @ vw2 + b2 (N=128 in two halves).
// ---------------------------------------------------------------------------
__global__ __launch_bounds__(256) void node_layer_mfma(
    float* __restrict__ h, unsigned short* __restrict__ hb,
    const unsigned short* __restrict__ mb,
    const unsigned short* __restrict__ vw1T,  // [64][192]
    const unsigned short* __restrict__ vw2T,  // [128][64]
    const float* __restrict__ b1, const float* __restrict__ b2) {
  __shared__ unsigned short Us[4][64 * UP];
  const int lane = threadIdx.x & 63;
  const int wv   = threadIdx.x >> 6;
  const int quad = lane >> 4;
  const int lm   = lane & 15;
  const int wid  = blockIdx.x * 4 + wv;
  const int ntiles = (Nn + 63) / 64;  // 782
  const bool act = wid < ntiles;
  const int i0 = wid * 64;
  unsigned short* us = Us[wv];

  bool mv[4];
#pragma unroll
  for (int mt = 0; mt < 4; ++mt) mv[mt] = act && (i0 + mt * 16) < Nn;

  if (act) {
    f4 acc[4][4];
#pragma unroll
    for (int mt = 0; mt < 4; ++mt)
#pragma unroll
      for (int nt = 0; nt < 4; ++nt) acc[mt][nt] = f4{0.f, 0.f, 0.f, 0.f};
#pragma unroll
    for (int ks = 0; ks < 6; ++ks) {
      const int kb = ks * 32 + quad * 8;
      sh8 a[4], b[4];
#pragma unroll
      for (int mt = 0; mt < 4; ++mt) {
        const int row = i0 + mt * 16 + lm;
        if (mv[mt]) {
          if (ks < 4) a[mt] = *(const sh8*)(hb + (long)row * DN + kb);
          else        a[mt] = *(const sh8*)(mb + (long)row * DE + (kb - 128));
        } else a[mt] = (sh8)0;
      }
#pragma unroll
      for (int nt = 0; nt < 4; ++nt)
        b[nt] = *(const sh8*)(vw1T + (nt * 16 + lm) * 192 + kb);
#pragma unroll
      for (int mt = 0; mt < 4; ++mt)
#pragma unroll
        for (int nt = 0; nt < 4; ++nt)
          acc[mt][nt] = mfma16(a[mt], b[nt], acc[mt][nt]);
    }
    float b1v[4];
#pragma unroll
    for (int nt = 0; nt < 4; ++nt) b1v[nt] = b1[nt * 16 + lm];
#pragma unroll
    for (int mt = 0; mt < 4; ++mt)
#pragma unroll
      for (int nt = 0; nt < 4; ++nt)
#pragma unroll
        for (int r = 0; r < 4; ++r) {
          const int row = mt * 16 + quad * 4 + r;
          const int col = nt * 16 + lm;
          us[row * UP + col] = f2bf(fmaxf(acc[mt][nt][r] + b1v[nt], 0.f));
        }
  }
  __syncthreads();
  if (act) {
#pragma unroll
    for (int nh = 0; nh < 2; ++nh) {
      f4 acc2[4][4];
#pragma unroll
      for (int mt = 0; mt < 4; ++mt)
#pragma unroll
        for (int nt = 0; nt < 4; ++nt) acc2[mt][nt] = f4{0.f, 0.f, 0.f, 0.f};
#pragma unroll
      for (int ks = 0; ks < 2; ++ks) {
        const int kb = ks * 32 + quad * 8;
        sh8 a[4], b[4];
#pragma unroll
        for (int mt = 0; mt < 4; ++mt)
          a[mt] = *(const sh8*)&us[(mt * 16 + lm) * UP + kb];
#pragma unroll
        for (int nt = 0; nt < 4; ++nt)
          b[nt] = *(const sh8*)(vw2T + (nh * 64 + nt * 16 + lm) * 64 + kb);
#pragma unroll
        for (int mt = 0; mt < 4; ++mt)
#pragma unroll
          for (int nt = 0; nt < 4; ++nt)
            acc2[mt][nt] = mfma16(a[mt], b[nt], acc2[mt][nt]);
      }
      float b2v[4];
#pragma unroll
      for (int nt = 0; nt < 4; ++nt) b2v[nt] = b2[nh * 64 + nt * 16 + lm];
#pragma unroll
      for (int mt = 0; mt < 4; ++mt) {
        if (!mv[mt]) continue;
#pragma unroll
        for (int r = 0; r < 4; ++r) {
          const int row = i0 + mt * 16 + quad * 4 + r;
#pragma unroll
          for (int nt = 0; nt < 4; ++nt) {
            const int col = nh * 64 + nt * 16 + lm;
            const float out = h[(long)row * DN + col] + acc2[mt][nt][r] + b2v[nt];
            h[(long)row * DN + col] = out;
            hb[(long)row * DN + col] = f2bf(out);
          }
        }
      }
    }
  }
}

// ---------------------------------------------------------------------------
// Readout (fp32)
// ---------------------------------------------------------------------------
__global__ __launch_bounds__(128) void graph_acc(const float* __restrict__ h,
                                                 const int* __restrict__ batch,
                                                 float* __restrict__ gacc,
                                                 float* __restrict__ gcnt) {
  const int i = blockIdx.x, c = threadIdx.x;
  const int b = batch[i];
  atomicAdd(&gacc[b * DN + c], h[(long)i * DN + c]);
  if (c == 0) atomicAdd(&gcnt[b], 1.0f);
}

__global__ __launch_bounds__(128) void readout(const float* __restrict__ gacc,
                                               const float* __restrict__ gcnt,
                                               const float* __restrict__ w1,
                                               const float* __restrict__ b1,
                                               const float* __restrict__ w2,
                                               const float* __restrict__ b2,
                                               float* __restrict__ out) {
  __shared__ float g[DN], t1[DN];
  const int b = blockIdx.x, c = threadIdx.x;
  const float inv = 1.0f / fmaxf(gcnt[b], 1.0f);
  g[c] = gacc[b * DN + c] * inv;
  __syncthreads();
  float acc = b1[c];
  for (int k = 0; k < DN; ++k) acc += g[k] * w1[k * DN + c];
  t1[c] = fmaxf(acc, 0.0f);
  __syncthreads();
  acc = b2[c];
  for (int k = 0; k < DN; ++k) acc += t1[k] * w2[k * DN + c];
  out[b * DN + c] = acc;
}

// ---------------------------------------------------------------------------
// Launch
// ---------------------------------------------------------------------------
extern "C" void kernel_launch(void* const* d_in, const int* in_sizes, int n_in,
                              void* d_out, int out_size, void* d_ws, size_t ws_size,
                              hipStream_t stream) {
  const float* x       = (const float*)d_in[0];
  const float* ea      = (const float*)d_in[1];
  const int*   ei      = (const int*)d_in[2];
  const int*   batch   = (const int*)d_in[3];
  const float* lin_x_w = (const float*)d_in[4];
  const float* lin_x_b = (const float*)d_in[5];
  const float* lin_e_w = (const float*)d_in[6];
  const float* lin_e_b = (const float*)d_in[7];
  const float* msg_w   = (const float*)d_in[8];
  const float* phie_w1 = (const float*)d_in[9];
  const float* phie_b1 = (const float*)d_in[10];
  const float* phie_w2 = (const float*)d_in[11];
  const float* phie_b2 = (const float*)d_in[12];
  const float* phiv_w1 = (const float*)d_in[13];
  const float* phiv_b1 = (const float*)d_in[14];
  const float* phiv_w2 = (const float*)d_in[15];
  const float* phiv_b2 = (const float*)d_in[16];
  const float* ro_w1   = (const float*)d_in[17];
  const float* ro_b1   = (const float*)d_in[18];
  const float* ro_w2   = (const float*)d_in[19];
  const float* ro_b2   = (const float*)d_in[20];

  const int* srcp = ei;
  const int* dstp = ei + Ne;

  // fp32 region
  float* h      = (float*)d_ws;                 // N*128
  float* e      = h + (long)Nn * DN;            // E*64
  float* m      = e + (long)Ne * DE;            // N*64
  float* invdeg = m + (long)Nn * DE;            // N
  float* gacc   = invdeg + Nn;                  // B*128
  float* gcnt   = gacc + Bg * DN;               // B
  // bf16 region
  unsigned short* hb   = (unsigned short*)(gcnt + Bg);
  unsigned short* eb   = hb + (long)Nn * DN;
  unsigned short* mb   = eb + (long)Ne * DE;
  unsigned short* weT  = mb + (long)Nn * DE;     // L*64*320
  unsigned short* ew2T = weT + (long)LAY * 64 * 320;
  unsigned short* vw1T = ew2T + (long)LAY * 64 * 64;
  unsigned short* vw2T = vw1T + (long)LAY * 64 * 192;

  hipMemsetAsync(invdeg, 0, sizeof(float) * (Nn + Bg * DN + Bg), stream);

  prep_we<<<LAY * 64, 64, 0, stream>>>(phie_w1, msg_w, phie_w2, weT, ew2T);
  prep_wv<<<LAY * 128, 64, 0, stream>>>(phiv_w1, phiv_w2, vw1T, vw2T);
  enc_node<<<Nn, 128, 0, stream>>>(x, lin_x_w, lin_x_b, h, hb);
  enc_edge<<<Ne / 4, 256, 0, stream>>>(ea, lin_e_w, lin_e_b, e, eb);
  deg_count<<<(Ne + 255) / 256, 256, 0, stream>>>(dstp, invdeg);
  deg_inv<<<(Nn + 255) / 256, 256, 0, stream>>>(invdeg);

  const int etiles = Ne / 64;              // 3125
  const int eblocks = (etiles + 3) / 4;    // 782
  const int vtiles = (Nn + 63) / 64;       // 782
  const int vblocks = (vtiles + 3) / 4;    // 196

  for (int l = 0; l < LAY; ++l) {
    hipMemsetAsync(m, 0, sizeof(float) * (long)Nn * DE, stream);
    edge_layer_mfma<<<eblocks, 256, 0, stream>>>(
        hb, e, eb, m, srcp, dstp,
        weT + (long)l * 64 * 320, ew2T + (long)l * 64 * 64,
        phie_b1 + (long)l * HD, phie_b2 + (long)l * DE);
    node_prep<<<((long)Nn * DE + 255) / 256, 256, 0, stream>>>(m, invdeg, mb);
    node_layer_mfma<<<vblocks, 256, 0, stream>>>(
        h, hb, mb,
        vw1T + (long)l * 64 * 192, vw2T + (long)l * 128 * 64,
        phiv_b1 + (long)l * HD, phiv_b2 + (long)l * DN);
  }

  graph_acc<<<Nn, 128, 0, stream>>>(h, batch, gacc, gcnt);
  readout<<<Bg, 128, 0, stream>>>(gacc, gcnt, ro_w1, ro_b1, ro_w2, ro_b2,
                                  (float*)d_out);
}

// Round 3
// 1073.528 us; speedup vs baseline: 7.9148x; 1.2901x over previous
//
#include <hip/hip_runtime.h>

// Problem constants
constexpr int Nn  = 50000;
constexpr int Ne  = 200000;
constexpr int Bg  = 64;
constexpr int DN  = 128;
constexpr int DE  = 64;
constexpr int HD  = 64;
constexpr int INN = 64;
constexpr int INE = 16;
constexpr int LAY = 6;

typedef __attribute__((ext_vector_type(8))) short sh8;  // 8 bf16 = 4 VGPR
typedef __attribute__((ext_vector_type(4))) float f4;   // C/D frag

__device__ inline unsigned short f2bf(float x) {
  union { float f; unsigned u; } v; v.f = x;
  unsigned r = v.u + 0x7FFF + ((v.u >> 16) & 1);  // RNE
  return (unsigned short)(r >> 16);
}

__device__ inline f4 mfma16(sh8 a, sh8 b, f4 c) {
  return __builtin_amdgcn_mfma_f32_16x16x32_bf16(a, b, c, 0, 0, 0);
}

// ---------------------------------------------------------------------------
// Weight prep (runs every launch; trivial cost).
// weT[l][n][k], k in [0,320): fused W1s (k<128), W1d (128..255), W1e (256..319)
// ew2T[l][n][k] k<64 ; vw1T[l][n][k] k<192 ; vw2T[l][n][k] n<128,k<64
// ---------------------------------------------------------------------------
__global__ __launch_bounds__(64) void prep_we(const float* __restrict__ ew1,
                                              const float* __restrict__ mw,
                                              const float* __restrict__ ew2,
                                              unsigned short* __restrict__ weT,
                                              unsigned short* __restrict__ ew2T) {
  const int l = blockIdx.x >> 6, n = blockIdx.x & 63, t = threadIdx.x;
  const float* E1 = ew1 + (long)l * 320 * 64;
  const float* MW = mw + (long)l * 128 * 64;
  const float* E2 = ew2 + (long)l * 64 * 64;
  unsigned short* W = weT + (long)l * 64 * 320 + (long)n * 320;
  __shared__ float c[64];
  c[t] = E1[(256 + t) * 64 + n];
  __syncthreads();
  for (int k = t; k < 128; k += 64) {
    float s = E1[k * 64 + n];
    for (int j = 0; j < 64; ++j) s += MW[k * 64 + j] * c[j];
    W[k] = f2bf(s);
  }
  for (int k = 128 + t; k < 320; k += 64) W[k] = f2bf(E1[k * 64 + n]);
  ew2T[(long)l * 64 * 64 + n * 64 + t] = f2bf(E2[t * 64 + n]);
}

__global__ __launch_bounds__(64) void prep_wv(const float* __restrict__ vw1,
                                              const float* __restrict__ vw2,
                                              unsigned short* __restrict__ vw1T,
                                              unsigned short* __restrict__ vw2T) {
  const int l = blockIdx.x >> 7, n = blockIdx.x & 127, t = threadIdx.x;
  vw2T[(long)l * 128 * 64 + n * 64 + t] = f2bf(vw2[(long)l * 64 * 128 + t * 128 + n]);
  if (n < 64) {
    for (int k = t; k < 192; k += 64)
      vw1T[(long)l * 64 * 192 + n * 192 + k] = f2bf(vw1[(long)l * 192 * 64 + k * 64 + n]);
  }
}

// ---------------------------------------------------------------------------
// Encoders (fp32 math, also write bf16 mirrors)
// ---------------------------------------------------------------------------
__global__ __launch_bounds__(128) void enc_node(const float* __restrict__ x,
                                                const float* __restrict__ w,
                                                const float* __restrict__ b,
                                                float* __restrict__ h,
                                                unsigned short* __restrict__ hb) {
  __shared__ float xs[INN];
  const int i = blockIdx.x, t = threadIdx.x;
  if (t < INN) xs[t] = x[(long)i * INN + t];
  __syncthreads();
  float acc = b[t];
  for (int k = 0; k < INN; ++k) acc += xs[k] * w[k * DN + t];
  h[(long)i * DN + t] = acc;
  hb[(long)i * DN + t] = f2bf(acc);
}

__global__ __launch_bounds__(256) void enc_edge(const float* __restrict__ ea,
                                                const float* __restrict__ w,
                                                const float* __restrict__ b,
                                                float* __restrict__ e,
                                                unsigned short* __restrict__ eb) {
  const int j = blockIdx.x * 4 + (threadIdx.x >> 6);
  const int c = threadIdx.x & 63;
  if (j >= Ne) return;
  const float* row = ea + (long)j * INE;
  float acc = b[c];
  for (int k = 0; k < INE; ++k) acc += row[k] * w[k * DE + c];
  e[(long)j * DE + c] = acc;
  eb[(long)j * DE + c] = f2bf(acc);
}

__global__ void deg_count(const int* __restrict__ dst, float* __restrict__ deg) {
  const int j = blockIdx.x * blockDim.x + threadIdx.x;
  if (j < Ne) atomicAdd(&deg[dst[j]], 1.0f);
}
__global__ void deg_inv(float* __restrict__ deg) {
  const int i = blockIdx.x * blockDim.x + threadIdx.x;
  if (i < Nn) deg[i] = 1.0f / fmaxf(deg[i], 1.0f);
}

// ---------------------------------------------------------------------------
// Edge layer (MFMA). Wave = 64 edges. A = [hb[src] | hb[dst] | eb] (K=320).
// u = relu(A @ W1 + b1); e' = e + u @ W2 + b2; scatter-add e' into m[dst].
// ---------------------------------------------------------------------------
constexpr int UP = 72;  // Us pitch (bf16 elems): 144B, 16B-aligned, 2-way banks

__global__ __launch_bounds__(256) void edge_layer_mfma(
    const unsigned short* __restrict__ hb,
    float* __restrict__ e, unsigned short* __restrict__ eb,
    float* __restrict__ m,
    const int* __restrict__ src, const int* __restrict__ dst,
    const unsigned short* __restrict__ weT,   // [64][320]
    const unsigned short* __restrict__ ew2T,  // [64][64]
    const float* __restrict__ b1, const float* __restrict__ b2) {
  __shared__ unsigned short Us[4][64 * UP];
  const int lane = threadIdx.x & 63;
  const int wv   = threadIdx.x >> 6;
  const int quad = lane >> 4;
  const int lm   = lane & 15;
  const int wid  = blockIdx.x * 4 + wv;
  const int ntiles = Ne / 64;  // 3125
  const bool act = wid < ntiles;
  const int j0 = wid * 64;
  unsigned short* us = Us[wv];

  if (act) {
    int aoff_s[4], aoff_d[4], aoff_e[4];
#pragma unroll
    for (int mt = 0; mt < 4; ++mt) {
      const int j = j0 + mt * 16 + lm;
      aoff_s[mt] = src[j] * DN;
      aoff_d[mt] = dst[j] * DN;
      aoff_e[mt] = j * DE;
    }
    f4 acc[4][4];
#pragma unroll
    for (int mt = 0; mt < 4; ++mt)
#pragma unroll
      for (int nt = 0; nt < 4; ++nt) acc[mt][nt] = f4{0.f, 0.f, 0.f, 0.f};

#pragma unroll
    for (int ks = 0; ks < 10; ++ks) {
      const int kb = ks * 32 + quad * 8;
      sh8 a[4], b[4];
#pragma unroll
      for (int mt = 0; mt < 4; ++mt) {
        const unsigned short* ap;
        if (ks < 4)      ap = hb + aoff_s[mt] + kb;
        else if (ks < 8) ap = hb + aoff_d[mt] + (kb - 128);
        else             ap = eb + aoff_e[mt] + (kb - 256);
        a[mt] = *(const sh8*)ap;
      }
#pragma unroll
      for (int nt = 0; nt < 4; ++nt)
        b[nt] = *(const sh8*)(weT + (nt * 16 + lm) * 320 + kb);
#pragma unroll
      for (int mt = 0; mt < 4; ++mt)
#pragma unroll
        for (int nt = 0; nt < 4; ++nt)
          acc[mt][nt] = mfma16(a[mt], b[nt], acc[mt][nt]);
    }
    // u epilogue: bias + relu, C-layout -> Us[row][col]
    float b1v[4];
#pragma unroll
    for (int nt = 0; nt < 4; ++nt) b1v[nt] = b1[nt * 16 + lm];
#pragma unroll
    for (int mt = 0; mt < 4; ++mt)
#pragma unroll
      for (int nt = 0; nt < 4; ++nt)
#pragma unroll
        for (int r = 0; r < 4; ++r) {
          const int row = mt * 16 + quad * 4 + r;
          const int col = nt * 16 + lm;
          us[row * UP + col] = f2bf(fmaxf(acc[mt][nt][r] + b1v[nt], 0.f));
        }
  }
  __syncthreads();
  if (act) {
    f4 acc2[4][4];
#pragma unroll
    for (int mt = 0; mt < 4; ++mt)
#pragma unroll
      for (int nt = 0; nt < 4; ++nt) acc2[mt][nt] = f4{0.f, 0.f, 0.f, 0.f};
#pragma unroll
    for (int ks = 0; ks < 2; ++ks) {
      const int kb = ks * 32 + quad * 8;
      sh8 a[4], b[4];
#pragma unroll
      for (int mt = 0; mt < 4; ++mt)
        a[mt] = *(const sh8*)&us[(mt * 16 + lm) * UP + kb];
#pragma unroll
      for (int nt = 0; nt < 4; ++nt)
        b[nt] = *(const sh8*)(ew2T + (nt * 16 + lm) * 64 + kb);
#pragma unroll
      for (int mt = 0; mt < 4; ++mt)
#pragma unroll
        for (int nt = 0; nt < 4; ++nt)
          acc2[mt][nt] = mfma16(a[mt], b[nt], acc2[mt][nt]);
    }
    float b2v[4];
#pragma unroll
    for (int nt = 0; nt < 4; ++nt) b2v[nt] = b2[nt * 16 + lm];
#pragma unroll
    for (int mt = 0; mt < 4; ++mt)
#pragma unroll
      for (int r = 0; r < 4; ++r) {
        const int j = j0 + mt * 16 + quad * 4 + r;
        const int dj = dst[j];
#pragma unroll
        for (int nt = 0; nt < 4; ++nt) {
          const int col = nt * 16 + lm;
          const float out = e[(long)j * DE + col] + acc2[mt][nt][r] + b2v[nt];
          e[(long)j * DE + col] = out;
          eb[(long)j * DE + col] = f2bf(out);
          atomicAdd(&m[(long)dj * DE + col], out);
        }
      }
  }
}

// ---------------------------------------------------------------------------
// mb = bf16(m * invdeg)
// ---------------------------------------------------------------------------
__global__ void node_prep(const float* __restrict__ m,
                          const float* __restrict__ invdeg,
                          unsigned short* __restrict__ mb) {
  const long i = (long)blockIdx.x * blockDim.x + threadIdx.x;
  if (i < (long)Nn * DE) mb[i] = f2bf(m[i] * invdeg[i >> 6]);
}

// ---------------------------------------------------------------------------
// Node layer (MFMA). Wave = 64 nodes. A = [hb | mb] (K=192).
// u = relu(A @ vw1 + b1); h' = h + u @ vw2 + b2 (N=128 in two halves).
// ---------------------------------------------------------------------------
__global__ __launch_bounds__(256) void node_layer_mfma(
    float* __restrict__ h, unsigned short* __restrict__ hb,
    const unsigned short* __restrict__ mb,
    const unsigned short* __restrict__ vw1T,  // [64][192]
    const unsigned short* __restrict__ vw2T,  // [128][64]
    const float* __restrict__ b1, const float* __restrict__ b2) {
  __shared__ unsigned short Us[4][64 * UP];
  const int lane = threadIdx.x & 63;
  const int wv   = threadIdx.x >> 6;
  const int quad = lane >> 4;
  const int lm   = lane & 15;
  const int wid  = blockIdx.x * 4 + wv;
  const int ntiles = (Nn + 63) / 64;  // 782
  const bool act = wid < ntiles;
  const int i0 = wid * 64;
  unsigned short* us = Us[wv];

  bool mv[4];
#pragma unroll
  for (int mt = 0; mt < 4; ++mt) mv[mt] = act && (i0 + mt * 16) < Nn;

  if (act) {
    f4 acc[4][4];
#pragma unroll
    for (int mt = 0; mt < 4; ++mt)
#pragma unroll
      for (int nt = 0; nt < 4; ++nt) acc[mt][nt] = f4{0.f, 0.f, 0.f, 0.f};
#pragma unroll
    for (int ks = 0; ks < 6; ++ks) {
      const int kb = ks * 32 + quad * 8;
      sh8 a[4], b[4];
#pragma unroll
      for (int mt = 0; mt < 4; ++mt) {
        const int row = i0 + mt * 16 + lm;
        if (mv[mt]) {
          if (ks < 4) a[mt] = *(const sh8*)(hb + (long)row * DN + kb);
          else        a[mt] = *(const sh8*)(mb + (long)row * DE + (kb - 128));
        } else a[mt] = (sh8)0;
      }
#pragma unroll
      for (int nt = 0; nt < 4; ++nt)
        b[nt] = *(const sh8*)(vw1T + (nt * 16 + lm) * 192 + kb);
#pragma unroll
      for (int mt = 0; mt < 4; ++mt)
#pragma unroll
        for (int nt = 0; nt < 4; ++nt)
          acc[mt][nt] = mfma16(a[mt], b[nt], acc[mt][nt]);
    }
    float b1v[4];
#pragma unroll
    for (int nt = 0; nt < 4; ++nt) b1v[nt] = b1[nt * 16 + lm];
#pragma unroll
    for (int mt = 0; mt < 4; ++mt)
#pragma unroll
      for (int nt = 0; nt < 4; ++nt)
#pragma unroll
        for (int r = 0; r < 4; ++r) {
          const int row = mt * 16 + quad * 4 + r;
          const int col = nt * 16 + lm;
          us[row * UP + col] = f2bf(fmaxf(acc[mt][nt][r] + b1v[nt], 0.f));
        }
  }
  __syncthreads();
  if (act) {
#pragma unroll
    for (int nh = 0; nh < 2; ++nh) {
      f4 acc2[4][4];
#pragma unroll
      for (int mt = 0; mt < 4; ++mt)
#pragma unroll
        for (int nt = 0; nt < 4; ++nt) acc2[mt][nt] = f4{0.f, 0.f, 0.f, 0.f};
#pragma unroll
      for (int ks = 0; ks < 2; ++ks) {
        const int kb = ks * 32 + quad * 8;
        sh8 a[4], b[4];
#pragma unroll
        for (int mt = 0; mt < 4; ++mt)
          a[mt] = *(const sh8*)&us[(mt * 16 + lm) * UP + kb];
#pragma unroll
        for (int nt = 0; nt < 4; ++nt)
          b[nt] = *(const sh8*)(vw2T + (nh * 64 + nt * 16 + lm) * 64 + kb);
#pragma unroll
        for (int mt = 0; mt < 4; ++mt)
#pragma unroll
          for (int nt = 0; nt < 4; ++nt)
            acc2[mt][nt] = mfma16(a[mt], b[nt], acc2[mt][nt]);
      }
      float b2v[4];
#pragma unroll
      for (int nt = 0; nt < 4; ++nt) b2v[nt] = b2[nh * 64 + nt * 16 + lm];
#pragma unroll
      for (int mt = 0; mt < 4; ++mt) {
        if (!mv[mt]) continue;
#pragma unroll
        for (int r = 0; r < 4; ++r) {
          const int row = i0 + mt * 16 + quad * 4 + r;
#pragma unroll
          for (int nt = 0; nt < 4; ++nt) {
            const int col = nh * 64 + nt * 16 + lm;
            const float out = h[(long)row * DN + col] + acc2[mt][nt][r] + b2v[nt];
            h[(long)row * DN + col] = out;
            hb[(long)row * DN + col] = f2bf(out);
          }
        }
      }
    }
  }
}

// ---------------------------------------------------------------------------
// Readout: segmented reduction over sorted batch (few atomics), then MLP.
// ---------------------------------------------------------------------------
constexpr int GB = 512;  // blocks for graph_acc

__global__ __launch_bounds__(128) void graph_acc(const float* __restrict__ h,
                                                 const int* __restrict__ batch,
                                                 float* __restrict__ gacc,
                                                 float* __restrict__ gcnt) {
  const int c = threadIdx.x;
  const int per = (Nn + GB - 1) / GB;  // 98
  const int s0 = blockIdx.x * per;
  const int s1 = min(s0 + per, Nn);
  if (s0 >= s1) return;
  int cur = batch[s0];
  float acc = 0.f, cnt = 0.f;
  for (int i = s0; i < s1; ++i) {
    const int b = batch[i];  // wave-uniform broadcast load
    if (b != cur) {          // wave-uniform branch (sorted batch)
      atomicAdd(&gacc[cur * DN + c], acc);
      if (c == 0) atomicAdd(&gcnt[cur], cnt);
      acc = 0.f; cnt = 0.f; cur = b;
    }
    acc += h[(long)i * DN + c];
    cnt += 1.f;
  }
  atomicAdd(&gacc[cur * DN + c], acc);
  if (c == 0) atomicAdd(&gcnt[cur], cnt);
}

__global__ __launch_bounds__(128) void readout(const float* __restrict__ gacc,
                                               const float* __restrict__ gcnt,
                                               const float* __restrict__ w1,
                                               const float* __restrict__ b1,
                                               const float* __restrict__ w2,
                                               const float* __restrict__ b2,
                                               float* __restrict__ out) {
  __shared__ float g[DN], t1[DN];
  const int b = blockIdx.x, c = threadIdx.x;
  const float inv = 1.0f / fmaxf(gcnt[b], 1.0f);
  g[c] = gacc[b * DN + c] * inv;
  __syncthreads();
  float acc = b1[c];
  for (int k = 0; k < DN; ++k) acc += g[k] * w1[k * DN + c];
  t1[c] = fmaxf(acc, 0.0f);
  __syncthreads();
  acc = b2[c];
  for (int k = 0; k < DN; ++k) acc += t1[k] * w2[k * DN + c];
  out[b * DN + c] = acc;
}

// ---------------------------------------------------------------------------
// Launch
// ---------------------------------------------------------------------------
extern "C" void kernel_launch(void* const* d_in, const int* in_sizes, int n_in,
                              void* d_out, int out_size, void* d_ws, size_t ws_size,
                              hipStream_t stream) {
  const float* x       = (const float*)d_in[0];
  const float* ea      = (const float*)d_in[1];
  const int*   ei      = (const int*)d_in[2];
  const int*   batch   = (const int*)d_in[3];
  const float* lin_x_w = (const float*)d_in[4];
  const float* lin_x_b = (const float*)d_in[5];
  const float* lin_e_w = (const float*)d_in[6];
  const float* lin_e_b = (const float*)d_in[7];
  const float* msg_w   = (const float*)d_in[8];
  const float* phie_w1 = (const float*)d_in[9];
  const float* phie_b1 = (const float*)d_in[10];
  const float* phie_w2 = (const float*)d_in[11];
  const float* phie_b2 = (const float*)d_in[12];
  const float* phiv_w1 = (const float*)d_in[13];
  const float* phiv_b1 = (const float*)d_in[14];
  const float* phiv_w2 = (const float*)d_in[15];
  const float* phiv_b2 = (const float*)d_in[16];
  const float* ro_w1   = (const float*)d_in[17];
  const float* ro_b1   = (const float*)d_in[18];
  const float* ro_w2   = (const float*)d_in[19];
  const float* ro_b2   = (const float*)d_in[20];

  const int* srcp = ei;
  const int* dstp = ei + Ne;

  // fp32 region
  float* h      = (float*)d_ws;                 // N*128
  float* e      = h + (long)Nn * DN;            // E*64
  float* m      = e + (long)Ne * DE;            // N*64
  float* invdeg = m + (long)Nn * DE;            // N
  float* gacc   = invdeg + Nn;                  // B*128
  float* gcnt   = gacc + Bg * DN;               // B
  // bf16 region
  unsigned short* hb   = (unsigned short*)(gcnt + Bg);
  unsigned short* eb   = hb + (long)Nn * DN;
  unsigned short* mb   = eb + (long)Ne * DE;
  unsigned short* weT  = mb + (long)Nn * DE;     // L*64*320
  unsigned short* ew2T = weT + (long)LAY * 64 * 320;
  unsigned short* vw1T = ew2T + (long)LAY * 64 * 64;
  unsigned short* vw2T = vw1T + (long)LAY * 64 * 192;

  hipMemsetAsync(invdeg, 0, sizeof(float) * (Nn + Bg * DN + Bg), stream);

  prep_we<<<LAY * 64, 64, 0, stream>>>(phie_w1, msg_w, phie_w2, weT, ew2T);
  prep_wv<<<LAY * 128, 64, 0, stream>>>(phiv_w1, phiv_w2, vw1T, vw2T);
  enc_node<<<Nn, 128, 0, stream>>>(x, lin_x_w, lin_x_b, h, hb);
  enc_edge<<<Ne / 4, 256, 0, stream>>>(ea, lin_e_w, lin_e_b, e, eb);
  deg_count<<<(Ne + 255) / 256, 256, 0, stream>>>(dstp, invdeg);
  deg_inv<<<(Nn + 255) / 256, 256, 0, stream>>>(invdeg);

  const int etiles = Ne / 64;              // 3125
  const int eblocks = (etiles + 3) / 4;    // 782
  const int vtiles = (Nn + 63) / 64;       // 782
  const int vblocks = (vtiles + 3) / 4;    // 196

  for (int l = 0; l < LAY; ++l) {
    hipMemsetAsync(m, 0, sizeof(float) * (long)Nn * DE, stream);
    edge_layer_mfma<<<eblocks, 256, 0, stream>>>(
        hb, e, eb, m, srcp, dstp,
        weT + (long)l * 64 * 320, ew2T + (long)l * 64 * 64,
        phie_b1 + (long)l * HD, phie_b2 + (long)l * DE);
    node_prep<<<((long)Nn * DE + 255) / 256, 256, 0, stream>>>(m, invdeg, mb);
    node_layer_mfma<<<vblocks, 256, 0, stream>>>(
        h, hb, mb,
        vw1T + (long)l * 64 * 192, vw2T + (long)l * 128 * 64,
        phiv_b1 + (long)l * HD, phiv_b2 + (long)l * DN);
  }

  graph_acc<<<GB, 128, 0, stream>>>(h, batch, gacc, gcnt);
  readout<<<Bg, 128, 0, stream>>>(gacc, gcnt, ro_w1, ro_b1, ro_w2, ro_b2,
                                  (float*)d_out);
}

// Round 4
// 933.271 us; speedup vs baseline: 9.1043x; 1.1503x over previous
//
#include <hip/hip_runtime.h>

// Problem constants
constexpr int Nn  = 50000;
constexpr int Ne  = 200000;
constexpr int Bg  = 64;
constexpr int DN  = 128;
constexpr int DE  = 64;
constexpr int HD  = 64;
constexpr int INN = 64;
constexpr int INE = 16;
constexpr int LAY = 6;

typedef __attribute__((ext_vector_type(8))) short sh8;  // 8 bf16 = 4 VGPR
typedef __attribute__((ext_vector_type(4))) float f4;   // C/D frag

__device__ inline unsigned short f2bf(float x) {
  union { float f; unsigned u; } v; v.f = x;
  unsigned r = v.u + 0x7FFF + ((v.u >> 16) & 1);  // RNE
  return (unsigned short)(r >> 16);
}
__device__ inline float bf2f(unsigned short u) {
  union { unsigned u; float f; } v; v.u = ((unsigned)u) << 16; return v.f;
}
__device__ inline f4 mfma16(sh8 a, sh8 b, f4 c) {
  return __builtin_amdgcn_mfma_f32_16x16x32_bf16(a, b, c, 0, 0, 0);
}

// ---------------------------------------------------------------------------
// Weight prep.
// weT[l][n][k], k in [0,320): fused W1s (k<128), W1d (128..255), W1e (256..319)
// ew2T[l][n][k] k<64 ; vw1T[l][n][k] k<192 ; vw2T[l][n][k] n<128,k<64
// ---------------------------------------------------------------------------
__global__ __launch_bounds__(64) void prep_we(const float* __restrict__ ew1,
                                              const float* __restrict__ mw,
                                              const float* __restrict__ ew2,
                                              unsigned short* __restrict__ weT,
                                              unsigned short* __restrict__ ew2T) {
  const int l = blockIdx.x >> 6, n = blockIdx.x & 63, t = threadIdx.x;
  const float* E1 = ew1 + (long)l * 320 * 64;
  const float* MW = mw + (long)l * 128 * 64;
  const float* E2 = ew2 + (long)l * 64 * 64;
  unsigned short* W = weT + (long)l * 64 * 320 + (long)n * 320;
  __shared__ float c[64];
  c[t] = E1[(256 + t) * 64 + n];
  __syncthreads();
  for (int k = t; k < 128; k += 64) {
    float s = E1[k * 64 + n];
    for (int j = 0; j < 64; ++j) s += MW[k * 64 + j] * c[j];
    W[k] = f2bf(s);
  }
  for (int k = 128 + t; k < 320; k += 64) W[k] = f2bf(E1[k * 64 + n]);
  ew2T[(long)l * 64 * 64 + n * 64 + t] = f2bf(E2[t * 64 + n]);
}

__global__ __launch_bounds__(64) void prep_wv(const float* __restrict__ vw1,
                                              const float* __restrict__ vw2,
                                              unsigned short* __restrict__ vw1T,
                                              unsigned short* __restrict__ vw2T) {
  const int l = blockIdx.x >> 7, n = blockIdx.x & 127, t = threadIdx.x;
  vw2T[(long)l * 128 * 64 + n * 64 + t] = f2bf(vw2[(long)l * 64 * 128 + t * 128 + n]);
  if (n < 64) {
    for (int k = t; k < 192; k += 64)
      vw1T[(long)l * 64 * 192 + n * 192 + k] = f2bf(vw1[(long)l * 192 * 64 + k * 64 + n]);
  }
}

// ---------------------------------------------------------------------------
// Encoders (fp32 math, bf16 outputs)
// ---------------------------------------------------------------------------
__global__ __launch_bounds__(128) void enc_node(const float* __restrict__ x,
                                                const float* __restrict__ w,
                                                const float* __restrict__ b,
                                                unsigned short* __restrict__ hb) {
  __shared__ float xs[INN];
  const int i = blockIdx.x, t = threadIdx.x;
  if (t < INN) xs[t] = x[(long)i * INN + t];
  __syncthreads();
  float acc = b[t];
  for (int k = 0; k < INN; ++k) acc += xs[k] * w[k * DN + t];
  hb[(long)i * DN + t] = f2bf(acc);
}

__global__ __launch_bounds__(256) void enc_edge(const float* __restrict__ ea,
                                                const float* __restrict__ w,
                                                const float* __restrict__ b,
                                                unsigned short* __restrict__ eb) {
  const int j = blockIdx.x * 4 + (threadIdx.x >> 6);
  const int c = threadIdx.x & 63;
  if (j >= Ne) return;
  const float* row = ea + (long)j * INE;
  float acc = b[c];
  for (int k = 0; k < INE; ++k) acc += row[k] * w[k * DE + c];
  eb[(long)j * DE + c] = f2bf(acc);
}

__global__ void deg_count(const int* __restrict__ dst, float* __restrict__ deg) {
  const int j = blockIdx.x * blockDim.x + threadIdx.x;
  if (j < Ne) atomicAdd(&deg[dst[j]], 1.0f);
}
__global__ void deg_inv(float* __restrict__ deg) {
  const int i = blockIdx.x * blockDim.x + threadIdx.x;
  if (i < Nn) deg[i] = 1.0f / fmaxf(deg[i], 1.0f);
}

// ---------------------------------------------------------------------------
// Edge layer (MFMA). Wave = 32 edges (2 M-tiles). A = [hb[src]|hb[dst]|eb], K=320.
// u = relu(A @ W1 + b1); e' = [u | e] @ [W2; I] + b2 (residual fused as
// identity MFMA reusing the eb A-fragments). Write eb; scatter-add into m.
// ---------------------------------------------------------------------------
constexpr int UP = 72;  // Us pitch (bf16): 144B rows

__global__ __launch_bounds__(256) void edge_layer_mfma(
    const unsigned short* __restrict__ hb,
    unsigned short* __restrict__ eb,
    float* __restrict__ m,
    const int* __restrict__ src, const int* __restrict__ dst,
    const unsigned short* __restrict__ weT,   // [64][320]
    const unsigned short* __restrict__ ew2T,  // [64][64]
    const float* __restrict__ b1, const float* __restrict__ b2) {
  __shared__ unsigned short Us[4][32 * UP];
  const int lane = threadIdx.x & 63;
  const int wv   = threadIdx.x >> 6;
  const int quad = lane >> 4;
  const int lm   = lane & 15;
  const int wid  = blockIdx.x * 4 + wv;
  const int ntiles = Ne / 32;  // 6250
  const bool act = wid < ntiles;
  const int j0 = wid * 32;
  unsigned short* us = Us[wv];

  sh8 ae[2][2];  // saved eb A-frags (K 256..319) for the residual identity

  if (act) {
    int aoff_s[2], aoff_d[2], aoff_e[2];
#pragma unroll
    for (int mt = 0; mt < 2; ++mt) {
      const int j = j0 + mt * 16 + lm;
      aoff_s[mt] = src[j] * DN;
      aoff_d[mt] = dst[j] * DN;
      aoff_e[mt] = j * DE;
    }
    f4 acc[2][4];
#pragma unroll
    for (int mt = 0; mt < 2; ++mt)
#pragma unroll
      for (int nt = 0; nt < 4; ++nt) acc[mt][nt] = f4{0.f, 0.f, 0.f, 0.f};

#pragma unroll
    for (int ks = 0; ks < 10; ++ks) {
      const int kb = ks * 32 + quad * 8;
      sh8 a[2], b[4];
#pragma unroll
      for (int mt = 0; mt < 2; ++mt) {
        const unsigned short* ap;
        if (ks < 4)      ap = hb + aoff_s[mt] + kb;
        else if (ks < 8) ap = hb + aoff_d[mt] + (kb - 128);
        else             ap = eb + aoff_e[mt] + (kb - 256);
        a[mt] = *(const sh8*)ap;
        if (ks >= 8) ae[mt][ks - 8] = a[mt];
      }
#pragma unroll
      for (int nt = 0; nt < 4; ++nt)
        b[nt] = *(const sh8*)(weT + (nt * 16 + lm) * 320 + kb);
#pragma unroll
      for (int mt = 0; mt < 2; ++mt)
#pragma unroll
        for (int nt = 0; nt < 4; ++nt)
          acc[mt][nt] = mfma16(a[mt], b[nt], acc[mt][nt]);
    }
    float b1v[4];
#pragma unroll
    for (int nt = 0; nt < 4; ++nt) b1v[nt] = b1[nt * 16 + lm];
#pragma unroll
    for (int mt = 0; mt < 2; ++mt)
#pragma unroll
      for (int nt = 0; nt < 4; ++nt)
#pragma unroll
        for (int r = 0; r < 4; ++r) {
          const int row = mt * 16 + quad * 4 + r;
          const int col = nt * 16 + lm;
          us[row * UP + col] = f2bf(fmaxf(acc[mt][nt][r] + b1v[nt], 0.f));
        }
  }
  __syncthreads();
  if (act) {
    f4 acc2[2][4];
#pragma unroll
    for (int mt = 0; mt < 2; ++mt)
#pragma unroll
      for (int nt = 0; nt < 4; ++nt) acc2[mt][nt] = f4{0.f, 0.f, 0.f, 0.f};
#pragma unroll
    for (int ks = 0; ks < 2; ++ks) {
      const int kb = ks * 32 + quad * 8;
      sh8 a[2], b[4];
#pragma unroll
      for (int mt = 0; mt < 2; ++mt)
        a[mt] = *(const sh8*)&us[(mt * 16 + lm) * UP + kb];
#pragma unroll
      for (int nt = 0; nt < 4; ++nt)
        b[nt] = *(const sh8*)(ew2T + (nt * 16 + lm) * 64 + kb);
#pragma unroll
      for (int mt = 0; mt < 2; ++mt)
#pragma unroll
        for (int nt = 0; nt < 4; ++nt)
          acc2[mt][nt] = mfma16(a[mt], b[nt], acc2[mt][nt]);
    }
    // residual: acc2 += Eb_tile @ I   (one MFMA per nt; ks2 = nt>>1)
#pragma unroll
    for (int nt = 0; nt < 4; ++nt) {
      const int d = nt * 16 + lm - (nt >> 1) * 32 - quad * 8;
      sh8 bi;
#pragma unroll
      for (int jj = 0; jj < 8; ++jj) bi[jj] = (d == jj) ? (short)0x3F80 : (short)0;
#pragma unroll
      for (int mt = 0; mt < 2; ++mt)
        acc2[mt][nt] = mfma16(ae[mt][nt >> 1], bi, acc2[mt][nt]);
    }
    float b2v[4];
#pragma unroll
    for (int nt = 0; nt < 4; ++nt) b2v[nt] = b2[nt * 16 + lm];
#pragma unroll
    for (int mt = 0; mt < 2; ++mt)
#pragma unroll
      for (int r = 0; r < 4; ++r) {
        const int j = j0 + mt * 16 + quad * 4 + r;
        const int dj = dst[j];
#pragma unroll
        for (int nt = 0; nt < 4; ++nt) {
          const int col = nt * 16 + lm;
          const float out = acc2[mt][nt][r] + b2v[nt];
          eb[(long)j * DE + col] = f2bf(out);
          atomicAdd(&m[(long)dj * DE + col], out);
        }
      }
  }
}

// ---------------------------------------------------------------------------
// mb = bf16(m * invdeg)
// ---------------------------------------------------------------------------
__global__ void node_prep(const float* __restrict__ m,
                          const float* __restrict__ invdeg,
                          unsigned short* __restrict__ mb) {
  const long i = (long)blockIdx.x * blockDim.x + threadIdx.x;
  if (i < (long)Nn * DE) mb[i] = f2bf(m[i] * invdeg[i >> 6]);
}

// ---------------------------------------------------------------------------
// Node layer (MFMA). Wave = 32 nodes (2 M-tiles). A = [hb | mb], K=192.
// u = relu(A @ vw1 + b1); h' = [u | h] @ [vw2; I] + b2 (residual fused).
// ---------------------------------------------------------------------------
__global__ __launch_bounds__(256) void node_layer_mfma(
    unsigned short* __restrict__ hb,
    const unsigned short* __restrict__ mb,
    const unsigned short* __restrict__ vw1T,  // [64][192]
    const unsigned short* __restrict__ vw2T,  // [128][64]
    const float* __restrict__ b1, const float* __restrict__ b2) {
  __shared__ unsigned short Us[4][32 * UP];
  const int lane = threadIdx.x & 63;
  const int wv   = threadIdx.x >> 6;
  const int quad = lane >> 4;
  const int lm   = lane & 15;
  const int wid  = blockIdx.x * 4 + wv;
  const int ntiles = (Nn + 31) / 32;  // 1563
  const bool act = wid < ntiles;
  const int i0 = wid * 32;
  unsigned short* us = Us[wv];

  bool mv[2];
#pragma unroll
  for (int mt = 0; mt < 2; ++mt) mv[mt] = act && (i0 + mt * 16) < Nn;

  sh8 ah[2][4];  // saved hb A-frags (K 0..127) for the residual identity

  if (act) {
    f4 acc[2][4];
#pragma unroll
    for (int mt = 0; mt < 2; ++mt)
#pragma unroll
      for (int nt = 0; nt < 4; ++nt) acc[mt][nt] = f4{0.f, 0.f, 0.f, 0.f};
#pragma unroll
    for (int ks = 0; ks < 6; ++ks) {
      const int kb = ks * 32 + quad * 8;
      sh8 a[2], b[4];
#pragma unroll
      for (int mt = 0; mt < 2; ++mt) {
        const int row = i0 + mt * 16 + lm;
        if (mv[mt]) {
          if (ks < 4) a[mt] = *(const sh8*)(hb + (long)row * DN + kb);
          else        a[mt] = *(const sh8*)(mb + (long)row * DE + (kb - 128));
        } else a[mt] = (sh8)0;
        if (ks < 4) ah[mt][ks] = a[mt];
      }
#pragma unroll
      for (int nt = 0; nt < 4; ++nt)
        b[nt] = *(const sh8*)(vw1T + (nt * 16 + lm) * 192 + kb);
#pragma unroll
      for (int mt = 0; mt < 2; ++mt)
#pragma unroll
        for (int nt = 0; nt < 4; ++nt)
          acc[mt][nt] = mfma16(a[mt], b[nt], acc[mt][nt]);
    }
    float b1v[4];
#pragma unroll
    for (int nt = 0; nt < 4; ++nt) b1v[nt] = b1[nt * 16 + lm];
#pragma unroll
    for (int mt = 0; mt < 2; ++mt)
#pragma unroll
      for (int nt = 0; nt < 4; ++nt)
#pragma unroll
        for (int r = 0; r < 4; ++r) {
          const int row = mt * 16 + quad * 4 + r;
          const int col = nt * 16 + lm;
          us[row * UP + col] = f2bf(fmaxf(acc[mt][nt][r] + b1v[nt], 0.f));
        }
  }
  __syncthreads();
  if (act) {
    // identity B-frag pattern is independent of nh (offsets cancel)
    sh8 bi[4];
#pragma unroll
    for (int nt = 0; nt < 4; ++nt) {
      const int d = nt * 16 + lm - (nt >> 1) * 32 - quad * 8;
#pragma unroll
      for (int jj = 0; jj < 8; ++jj) bi[nt][jj] = (d == jj) ? (short)0x3F80 : (short)0;
    }
#pragma unroll
    for (int nh = 0; nh < 2; ++nh) {
      f4 acc2[2][4];
#pragma unroll
      for (int mt = 0; mt < 2; ++mt)
#pragma unroll
        for (int nt = 0; nt < 4; ++nt) acc2[mt][nt] = f4{0.f, 0.f, 0.f, 0.f};
#pragma unroll
      for (int ks = 0; ks < 2; ++ks) {
        const int kb = ks * 32 + quad * 8;
        sh8 a[2], b[4];
#pragma unroll
        for (int mt = 0; mt < 2; ++mt)
          a[mt] = *(const sh8*)&us[(mt * 16 + lm) * UP + kb];
#pragma unroll
        for (int nt = 0; nt < 4; ++nt)
          b[nt] = *(const sh8*)(vw2T + (nh * 64 + nt * 16 + lm) * 64 + kb);
#pragma unroll
        for (int mt = 0; mt < 2; ++mt)
#pragma unroll
          for (int nt = 0; nt < 4; ++nt)
            acc2[mt][nt] = mfma16(a[mt], b[nt], acc2[mt][nt]);
      }
      // residual: acc2 += Hb_tile(:, nh*64..) @ I  (ks2 = nh*2 + (nt>>1))
#pragma unroll
      for (int nt = 0; nt < 4; ++nt)
#pragma unroll
        for (int mt = 0; mt < 2; ++mt)
          acc2[mt][nt] = mfma16(ah[mt][nh * 2 + (nt >> 1)], bi[nt], acc2[mt][nt]);

      float b2v[4];
#pragma unroll
      for (int nt = 0; nt < 4; ++nt) b2v[nt] = b2[nh * 64 + nt * 16 + lm];
#pragma unroll
      for (int mt = 0; mt < 2; ++mt) {
        if (!mv[mt]) continue;
#pragma unroll
        for (int r = 0; r < 4; ++r) {
          const int row = i0 + mt * 16 + quad * 4 + r;
#pragma unroll
          for (int nt = 0; nt < 4; ++nt) {
            const int col = nh * 64 + nt * 16 + lm;
            hb[(long)row * DN + col] = f2bf(acc2[mt][nt][r] + b2v[nt]);
          }
        }
      }
    }
  }
}

// ---------------------------------------------------------------------------
// Readout: segmented reduction over sorted batch, then MLP.
// ---------------------------------------------------------------------------
constexpr int GB = 512;

__global__ __launch_bounds__(128) void graph_acc(const unsigned short* __restrict__ hb,
                                                 const int* __restrict__ batch,
                                                 float* __restrict__ gacc,
                                                 float* __restrict__ gcnt) {
  const int c = threadIdx.x;
  const int per = (Nn + GB - 1) / GB;  // 98
  const int s0 = blockIdx.x * per;
  const int s1 = min(s0 + per, Nn);
  if (s0 >= s1) return;
  int cur = batch[s0];
  float acc = 0.f, cnt = 0.f;
  for (int i = s0; i < s1; ++i) {
    const int b = batch[i];
    if (b != cur) {
      atomicAdd(&gacc[cur * DN + c], acc);
      if (c == 0) atomicAdd(&gcnt[cur], cnt);
      acc = 0.f; cnt = 0.f; cur = b;
    }
    acc += bf2f(hb[(long)i * DN + c]);
    cnt += 1.f;
  }
  atomicAdd(&gacc[cur * DN + c], acc);
  if (c == 0) atomicAdd(&gcnt[cur], cnt);
}

__global__ __launch_bounds__(128) void readout(const float* __restrict__ gacc,
                                               const float* __restrict__ gcnt,
                                               const float* __restrict__ w1,
                                               const float* __restrict__ b1,
                                               const float* __restrict__ w2,
                                               const float* __restrict__ b2,
                                               float* __restrict__ out) {
  __shared__ float g[DN], t1[DN];
  const int b = blockIdx.x, c = threadIdx.x;
  const float inv = 1.0f / fmaxf(gcnt[b], 1.0f);
  g[c] = gacc[b * DN + c] * inv;
  __syncthreads();
  float acc = b1[c];
  for (int k = 0; k < DN; ++k) acc += g[k] * w1[k * DN + c];
  t1[c] = fmaxf(acc, 0.0f);
  __syncthreads();
  acc = b2[c];
  for (int k = 0; k < DN; ++k) acc += t1[k] * w2[k * DN + c];
  out[b * DN + c] = acc;
}

// ---------------------------------------------------------------------------
// Launch
// ---------------------------------------------------------------------------
extern "C" void kernel_launch(void* const* d_in, const int* in_sizes, int n_in,
                              void* d_out, int out_size, void* d_ws, size_t ws_size,
                              hipStream_t stream) {
  const float* x       = (const float*)d_in[0];
  const float* ea      = (const float*)d_in[1];
  const int*   ei      = (const int*)d_in[2];
  const int*   batch   = (const int*)d_in[3];
  const float* lin_x_w = (const float*)d_in[4];
  const float* lin_x_b = (const float*)d_in[5];
  const float* lin_e_w = (const float*)d_in[6];
  const float* lin_e_b = (const float*)d_in[7];
  const float* msg_w   = (const float*)d_in[8];
  const float* phie_w1 = (const float*)d_in[9];
  const float* phie_b1 = (const float*)d_in[10];
  const float* phie_w2 = (const float*)d_in[11];
  const float* phie_b2 = (const float*)d_in[12];
  const float* phiv_w1 = (const float*)d_in[13];
  const float* phiv_b1 = (const float*)d_in[14];
  const float* phiv_w2 = (const float*)d_in[15];
  const float* phiv_b2 = (const float*)d_in[16];
  const float* ro_w1   = (const float*)d_in[17];
  const float* ro_b1   = (const float*)d_in[18];
  const float* ro_w2   = (const float*)d_in[19];
  const float* ro_b2   = (const float*)d_in[20];

  const int* srcp = ei;
  const int* dstp = ei + Ne;

  // fp32 region
  float* m      = (float*)d_ws;                 // N*64
  float* invdeg = m + (long)Nn * DE;            // N
  float* gacc   = invdeg + Nn;                  // B*128
  float* gcnt   = gacc + Bg * DN;               // B
  // bf16 region
  unsigned short* hb   = (unsigned short*)(gcnt + Bg);
  unsigned short* eb   = hb + (long)Nn * DN;
  unsigned short* mb   = eb + (long)Ne * DE;
  unsigned short* weT  = mb + (long)Nn * DE;     // L*64*320
  unsigned short* ew2T = weT + (long)LAY * 64 * 320;
  unsigned short* vw1T = ew2T + (long)LAY * 64 * 64;
  unsigned short* vw2T = vw1T + (long)LAY * 64 * 192;

  hipMemsetAsync(invdeg, 0, sizeof(float) * (Nn + Bg * DN + Bg), stream);

  prep_we<<<LAY * 64, 64, 0, stream>>>(phie_w1, msg_w, phie_w2, weT, ew2T);
  prep_wv<<<LAY * 128, 64, 0, stream>>>(phiv_w1, phiv_w2, vw1T, vw2T);
  enc_node<<<Nn, 128, 0, stream>>>(x, lin_x_w, lin_x_b, hb);
  enc_edge<<<Ne / 4, 256, 0, stream>>>(ea, lin_e_w, lin_e_b, eb);
  deg_count<<<(Ne + 255) / 256, 256, 0, stream>>>(dstp, invdeg);
  deg_inv<<<(Nn + 255) / 256, 256, 0, stream>>>(invdeg);

  const int etiles = Ne / 32;              // 6250
  const int eblocks = (etiles + 3) / 4;    // 1563
  const int vtiles = (Nn + 31) / 32;       // 1563
  const int vblocks = (vtiles + 3) / 4;    // 391

  for (int l = 0; l < LAY; ++l) {
    hipMemsetAsync(m, 0, sizeof(float) * (long)Nn * DE, stream);
    edge_layer_mfma<<<eblocks, 256, 0, stream>>>(
        hb, eb, m, srcp, dstp,
        weT + (long)l * 64 * 320, ew2T + (long)l * 64 * 64,
        phie_b1 + (long)l * HD, phie_b2 + (long)l * DE);
    node_prep<<<((long)Nn * DE + 255) / 256, 256, 0, stream>>>(m, invdeg, mb);
    node_layer_mfma<<<vblocks, 256, 0, stream>>>(
        hb, mb,
        vw1T + (long)l * 64 * 192, vw2T + (long)l * 128 * 64,
        phiv_b1 + (long)l * HD, phiv_b2 + (long)l * DN);
  }

  graph_acc<<<GB, 128, 0, stream>>>(hb, batch, gacc, gcnt);
  readout<<<Bg, 128, 0, stream>>>(gacc, gcnt, ro_w1, ro_b1, ro_w2, ro_b2,
                                  (float*)d_out);
}

// Round 5
// 836.863 us; speedup vs baseline: 10.1532x; 1.1152x over previous
//
#include <hip/hip_runtime.h>

// Problem constants
constexpr int Nn  = 50000;
constexpr int Ne  = 200000;
constexpr int Bg  = 64;
constexpr int DN  = 128;
constexpr int DE  = 64;
constexpr int HD  = 64;
constexpr int INN = 64;
constexpr int INE = 16;
constexpr int LAY = 6;
constexpr int SB  = 196;  // scan blocks: 196*256 >= Nn

typedef __attribute__((ext_vector_type(8))) short sh8;  // 8 bf16 = 4 VGPR
typedef __attribute__((ext_vector_type(4))) float f4;   // C/D frag

__device__ inline unsigned short f2bf(float x) {
  union { float f; unsigned u; } v; v.f = x;
  unsigned r = v.u + 0x7FFF + ((v.u >> 16) & 1);  // RNE
  return (unsigned short)(r >> 16);
}
__device__ inline float bf2f(unsigned short u) {
  union { unsigned u; float f; } v; v.u = ((unsigned)u) << 16; return v.f;
}
__device__ inline f4 mfma16(sh8 a, sh8 b, f4 c) {
  return __builtin_amdgcn_mfma_f32_16x16x32_bf16(a, b, c, 0, 0, 0);
}

// ---------------------------------------------------------------------------
// CSR build: histogram -> exclusive scan -> scatter (dst-sorted permutation)
// ---------------------------------------------------------------------------
__global__ void hist(const int* __restrict__ dst, int* __restrict__ deg) {
  const int j = blockIdx.x * blockDim.x + threadIdx.x;
  if (j < Ne) atomicAdd(&deg[dst[j]], 1);
}

__global__ __launch_bounds__(256) void scan1(const int* __restrict__ deg,
                                             int* __restrict__ rp,
                                             int* __restrict__ bsum) {
  __shared__ int s[256];
  const int t = threadIdx.x, i = blockIdx.x * 256 + t;
  const int v = (i < Nn) ? deg[i] : 0;
  s[t] = v; __syncthreads();
  for (int off = 1; off < 256; off <<= 1) {
    const int x = (t >= off) ? s[t - off] : 0;
    __syncthreads();
    s[t] += x;
    __syncthreads();
  }
  if (i < Nn) rp[i] = s[t] - v;  // intra-block exclusive
  if (t == 255) bsum[blockIdx.x] = s[255];
}

__global__ __launch_bounds__(256) void scan2(const int* __restrict__ bsum,
                                             int* __restrict__ boff) {
  __shared__ int s[256];
  const int t = threadIdx.x;
  const int v = (t < SB) ? bsum[t] : 0;
  s[t] = v; __syncthreads();
  for (int off = 1; off < 256; off <<= 1) {
    const int x = (t >= off) ? s[t - off] : 0;
    __syncthreads();
    s[t] += x;
    __syncthreads();
  }
  if (t < SB) boff[t] = s[t] - v;
}

__global__ __launch_bounds__(256) void scan3(int* __restrict__ rp,
                                             const int* __restrict__ boff,
                                             const int* __restrict__ deg,
                                             int* __restrict__ cursor,
                                             float* __restrict__ invdeg) {
  const int i = blockIdx.x * 256 + threadIdx.x;
  if (i < Nn) {
    const int r = rp[i] + boff[i >> 8];
    rp[i] = r;
    cursor[i] = r;
    invdeg[i] = 1.0f / fmaxf((float)deg[i], 1.0f);
  }
  if (i == 0) rp[Nn] = Ne;
}

__global__ void scatter(const int* __restrict__ src, const int* __restrict__ dst,
                        int* __restrict__ cursor, int* __restrict__ perm,
                        int* __restrict__ src_s, int* __restrict__ dst_s) {
  const int j = blockIdx.x * blockDim.x + threadIdx.x;
  if (j < Ne) {
    const int d = dst[j];
    const int p = atomicAdd(&cursor[d], 1);
    perm[p] = j;
    src_s[p] = src[j];
    dst_s[p] = d;
  }
}

// ---------------------------------------------------------------------------
// Weight prep.
// weT[l][n][k], k in [0,320): fused W1s (k<128), W1d (128..255), W1e (256..319)
// ---------------------------------------------------------------------------
__global__ __launch_bounds__(64) void prep_we(const float* __restrict__ ew1,
                                              const float* __restrict__ mw,
                                              const float* __restrict__ ew2,
                                              unsigned short* __restrict__ weT,
                                              unsigned short* __restrict__ ew2T) {
  const int l = blockIdx.x >> 6, n = blockIdx.x & 63, t = threadIdx.x;
  const float* E1 = ew1 + (long)l * 320 * 64;
  const float* MW = mw + (long)l * 128 * 64;
  const float* E2 = ew2 + (long)l * 64 * 64;
  unsigned short* W = weT + (long)l * 64 * 320 + (long)n * 320;
  __shared__ float c[64];
  c[t] = E1[(256 + t) * 64 + n];
  __syncthreads();
  for (int k = t; k < 128; k += 64) {
    float s = E1[k * 64 + n];
    for (int j = 0; j < 64; ++j) s += MW[k * 64 + j] * c[j];
    W[k] = f2bf(s);
  }
  for (int k = 128 + t; k < 320; k += 64) W[k] = f2bf(E1[k * 64 + n]);
  ew2T[(long)l * 64 * 64 + n * 64 + t] = f2bf(E2[t * 64 + n]);
}

__global__ __launch_bounds__(64) void prep_wv(const float* __restrict__ vw1,
                                              const float* __restrict__ vw2,
                                              unsigned short* __restrict__ vw1T,
                                              unsigned short* __restrict__ vw2T) {
  const int l = blockIdx.x >> 7, n = blockIdx.x & 127, t = threadIdx.x;
  vw2T[(long)l * 128 * 64 + n * 64 + t] = f2bf(vw2[(long)l * 64 * 128 + t * 128 + n]);
  if (n < 64) {
    for (int k = t; k < 192; k += 64)
      vw1T[(long)l * 64 * 192 + n * 192 + k] = f2bf(vw1[(long)l * 192 * 64 + k * 64 + n]);
  }
}

// ---------------------------------------------------------------------------
// Encoders (fp32 math, bf16 outputs; edges written in dst-sorted order)
// ---------------------------------------------------------------------------
__global__ __launch_bounds__(128) void enc_node(const float* __restrict__ x,
                                                const float* __restrict__ w,
                                                const float* __restrict__ b,
                                                unsigned short* __restrict__ hb) {
  __shared__ float xs[INN];
  const int i = blockIdx.x, t = threadIdx.x;
  if (t < INN) xs[t] = x[(long)i * INN + t];
  __syncthreads();
  float acc = b[t];
  for (int k = 0; k < INN; ++k) acc += xs[k] * w[k * DN + t];
  hb[(long)i * DN + t] = f2bf(acc);
}

__global__ __launch_bounds__(256) void enc_edge(const float* __restrict__ ea,
                                                const int* __restrict__ perm,
                                                const float* __restrict__ w,
                                                const float* __restrict__ b,
                                                unsigned short* __restrict__ eb) {
  const int j = blockIdx.x * 4 + (threadIdx.x >> 6);
  const int c = threadIdx.x & 63;
  if (j >= Ne) return;
  const float* row = ea + (long)perm[j] * INE;
  float acc = b[c];
  for (int k = 0; k < INE; ++k) acc += row[k] * w[k * DE + c];
  eb[(long)j * DE + c] = f2bf(acc);
}

// ---------------------------------------------------------------------------
// Edge layer (MFMA). Wave = 32 edges (2 M-tiles), dst-sorted order.
// A = [hb[src]|hb[dst]|eb], K=320. u = relu(A@W1+b1);
// e' = [u|e] @ [W2; I] + b2 (residual fused as identity MFMA). Writes eb only.
// ---------------------------------------------------------------------------
constexpr int UP = 72;  // Us pitch (bf16): 144B rows

__global__ __launch_bounds__(256) void edge_layer_mfma(
    const unsigned short* __restrict__ hb,
    unsigned short* __restrict__ eb,
    const int* __restrict__ src_s, const int* __restrict__ dst_s,
    const unsigned short* __restrict__ weT,   // [64][320]
    const unsigned short* __restrict__ ew2T,  // [64][64]
    const float* __restrict__ b1, const float* __restrict__ b2) {
  __shared__ unsigned short Us[4][32 * UP];
  const int lane = threadIdx.x & 63;
  const int wv   = threadIdx.x >> 6;
  const int quad = lane >> 4;
  const int lm   = lane & 15;
  const int wid  = blockIdx.x * 4 + wv;
  const int ntiles = Ne / 32;  // 6250
  const bool act = wid < ntiles;
  const int j0 = wid * 32;
  unsigned short* us = Us[wv];

  sh8 ae[2][2];  // saved eb A-frags (K 256..319) for the residual identity

  if (act) {
    int aoff_s[2], aoff_d[2], aoff_e[2];
#pragma unroll
    for (int mt = 0; mt < 2; ++mt) {
      const int j = j0 + mt * 16 + lm;
      aoff_s[mt] = src_s[j] * DN;
      aoff_d[mt] = dst_s[j] * DN;
      aoff_e[mt] = j * DE;
    }
    f4 acc[2][4];
#pragma unroll
    for (int mt = 0; mt < 2; ++mt)
#pragma unroll
      for (int nt = 0; nt < 4; ++nt) acc[mt][nt] = f4{0.f, 0.f, 0.f, 0.f};

#pragma unroll
    for (int ks = 0; ks < 10; ++ks) {
      const int kb = ks * 32 + quad * 8;
      sh8 a[2], b[4];
#pragma unroll
      for (int mt = 0; mt < 2; ++mt) {
        const unsigned short* ap;
        if (ks < 4)      ap = hb + aoff_s[mt] + kb;
        else if (ks < 8) ap = hb + aoff_d[mt] + (kb - 128);
        else             ap = eb + aoff_e[mt] + (kb - 256);
        a[mt] = *(const sh8*)ap;
        if (ks >= 8) ae[mt][ks - 8] = a[mt];
      }
#pragma unroll
      for (int nt = 0; nt < 4; ++nt)
        b[nt] = *(const sh8*)(weT + (nt * 16 + lm) * 320 + kb);
#pragma unroll
      for (int mt = 0; mt < 2; ++mt)
#pragma unroll
        for (int nt = 0; nt < 4; ++nt)
          acc[mt][nt] = mfma16(a[mt], b[nt], acc[mt][nt]);
    }
    float b1v[4];
#pragma unroll
    for (int nt = 0; nt < 4; ++nt) b1v[nt] = b1[nt * 16 + lm];
#pragma unroll
    for (int mt = 0; mt < 2; ++mt)
#pragma unroll
      for (int nt = 0; nt < 4; ++nt)
#pragma unroll
        for (int r = 0; r < 4; ++r) {
          const int row = mt * 16 + quad * 4 + r;
          const int col = nt * 16 + lm;
          us[row * UP + col] = f2bf(fmaxf(acc[mt][nt][r] + b1v[nt], 0.f));
        }
  }
  __syncthreads();
  if (act) {
    f4 acc2[2][4];
#pragma unroll
    for (int mt = 0; mt < 2; ++mt)
#pragma unroll
      for (int nt = 0; nt < 4; ++nt) acc2[mt][nt] = f4{0.f, 0.f, 0.f, 0.f};
#pragma unroll
    for (int ks = 0; ks < 2; ++ks) {
      const int kb = ks * 32 + quad * 8;
      sh8 a[2], b[4];
#pragma unroll
      for (int mt = 0; mt < 2; ++mt)
        a[mt] = *(const sh8*)&us[(mt * 16 + lm) * UP + kb];
#pragma unroll
      for (int nt = 0; nt < 4; ++nt)
        b[nt] = *(const sh8*)(ew2T + (nt * 16 + lm) * 64 + kb);
#pragma unroll
      for (int mt = 0; mt < 2; ++mt)
#pragma unroll
        for (int nt = 0; nt < 4; ++nt)
          acc2[mt][nt] = mfma16(a[mt], b[nt], acc2[mt][nt]);
    }
    // residual: acc2 += Eb_tile @ I (one MFMA per nt)
#pragma unroll
    for (int nt = 0; nt < 4; ++nt) {
      const int d = nt * 16 + lm - (nt >> 1) * 32 - quad * 8;
      sh8 bi;
#pragma unroll
      for (int jj = 0; jj < 8; ++jj) bi[jj] = (d == jj) ? (short)0x3F80 : (short)0;
#pragma unroll
      for (int mt = 0; mt < 2; ++mt)
        acc2[mt][nt] = mfma16(ae[mt][nt >> 1], bi, acc2[mt][nt]);
    }
    float b2v[4];
#pragma unroll
    for (int nt = 0; nt < 4; ++nt) b2v[nt] = b2[nt * 16 + lm];
#pragma unroll
    for (int mt = 0; mt < 2; ++mt)
#pragma unroll
      for (int r = 0; r < 4; ++r) {
        const int j = j0 + mt * 16 + quad * 4 + r;
#pragma unroll
        for (int nt = 0; nt < 4; ++nt) {
          const int col = nt * 16 + lm;
          eb[(long)j * DE + col] = f2bf(acc2[mt][nt][r] + b2v[nt]);
        }
      }
  }
}

// ---------------------------------------------------------------------------
// CSR segmented mean: mb[i] = bf16(invdeg[i] * sum_{j in rp[i]..rp[i+1]} eb[j])
// Wave per node, lane = channel; eb segment is contiguous (dst-sorted).
// ---------------------------------------------------------------------------
__global__ __launch_bounds__(256) void csr_mean(const unsigned short* __restrict__ eb,
                                                const int* __restrict__ rp,
                                                const float* __restrict__ invdeg,
                                                unsigned short* __restrict__ mb) {
  const int i = blockIdx.x * 4 + (threadIdx.x >> 6);
  const int c = threadIdx.x & 63;
  if (i >= Nn) return;
  const int s = rp[i], t = rp[i + 1];
  float sum = 0.f;
  for (int j = s; j < t; ++j) sum += bf2f(eb[(long)j * DE + c]);
  mb[(long)i * DE + c] = f2bf(sum * invdeg[i]);
}

// ---------------------------------------------------------------------------
// Node layer (MFMA). Wave = 32 nodes (2 M-tiles). A = [hb | mb], K=192.
// u = relu(A @ vw1 + b1); h' = [u | h] @ [vw2; I] + b2 (residual fused).
// ---------------------------------------------------------------------------
__global__ __launch_bounds__(256) void node_layer_mfma(
    unsigned short* __restrict__ hb,
    const unsigned short* __restrict__ mb,
    const unsigned short* __restrict__ vw1T,  // [64][192]
    const unsigned short* __restrict__ vw2T,  // [128][64]
    const float* __restrict__ b1, const float* __restrict__ b2) {
  __shared__ unsigned short Us[4][32 * UP];
  const int lane = threadIdx.x & 63;
  const int wv   = threadIdx.x >> 6;
  const int quad = lane >> 4;
  const int lm   = lane & 15;
  const int wid  = blockIdx.x * 4 + wv;
  const int ntiles = (Nn + 31) / 32;  // 1563
  const bool act = wid < ntiles;
  const int i0 = wid * 32;
  unsigned short* us = Us[wv];

  bool mv[2];
#pragma unroll
  for (int mt = 0; mt < 2; ++mt) mv[mt] = act && (i0 + mt * 16) < Nn;

  sh8 ah[2][4];  // saved hb A-frags (K 0..127) for the residual identity

  if (act) {
    f4 acc[2][4];
#pragma unroll
    for (int mt = 0; mt < 2; ++mt)
#pragma unroll
      for (int nt = 0; nt < 4; ++nt) acc[mt][nt] = f4{0.f, 0.f, 0.f, 0.f};
#pragma unroll
    for (int ks = 0; ks < 6; ++ks) {
      const int kb = ks * 32 + quad * 8;
      sh8 a[2], b[4];
#pragma unroll
      for (int mt = 0; mt < 2; ++mt) {
        const int row = i0 + mt * 16 + lm;
        if (mv[mt]) {
          if (ks < 4) a[mt] = *(const sh8*)(hb + (long)row * DN + kb);
          else        a[mt] = *(const sh8*)(mb + (long)row * DE + (kb - 128));
        } else a[mt] = (sh8)0;
        if (ks < 4) ah[mt][ks] = a[mt];
      }
#pragma unroll
      for (int nt = 0; nt < 4; ++nt)
        b[nt] = *(const sh8*)(vw1T + (nt * 16 + lm) * 192 + kb);
#pragma unroll
      for (int mt = 0; mt < 2; ++mt)
#pragma unroll
        for (int nt = 0; nt < 4; ++nt)
          acc[mt][nt] = mfma16(a[mt], b[nt], acc[mt][nt]);
    }
    float b1v[4];
#pragma unroll
    for (int nt = 0; nt < 4; ++nt) b1v[nt] = b1[nt * 16 + lm];
#pragma unroll
    for (int mt = 0; mt < 2; ++mt)
#pragma unroll
      for (int nt = 0; nt < 4; ++nt)
#pragma unroll
        for (int r = 0; r < 4; ++r) {
          const int row = mt * 16 + quad * 4 + r;
          const int col = nt * 16 + lm;
          us[row * UP + col] = f2bf(fmaxf(acc[mt][nt][r] + b1v[nt], 0.f));
        }
  }
  __syncthreads();
  if (act) {
    sh8 bi[4];
#pragma unroll
    for (int nt = 0; nt < 4; ++nt) {
      const int d = nt * 16 + lm - (nt >> 1) * 32 - quad * 8;
#pragma unroll
      for (int jj = 0; jj < 8; ++jj) bi[nt][jj] = (d == jj) ? (short)0x3F80 : (short)0;
    }
#pragma unroll
    for (int nh = 0; nh < 2; ++nh) {
      f4 acc2[2][4];
#pragma unroll
      for (int mt = 0; mt < 2; ++mt)
#pragma unroll
        for (int nt = 0; nt < 4; ++nt) acc2[mt][nt] = f4{0.f, 0.f, 0.f, 0.f};
#pragma unroll
      for (int ks = 0; ks < 2; ++ks) {
        const int kb = ks * 32 + quad * 8;
        sh8 a[2], b[4];
#pragma unroll
        for (int mt = 0; mt < 2; ++mt)
          a[mt] = *(const sh8*)&us[(mt * 16 + lm) * UP + kb];
#pragma unroll
        for (int nt = 0; nt < 4; ++nt)
          b[nt] = *(const sh8*)(vw2T + (nh * 64 + nt * 16 + lm) * 64 + kb);
#pragma unroll
        for (int mt = 0; mt < 2; ++mt)
#pragma unroll
          for (int nt = 0; nt < 4; ++nt)
            acc2[mt][nt] = mfma16(a[mt], b[nt], acc2[mt][nt]);
      }
#pragma unroll
      for (int nt = 0; nt < 4; ++nt)
#pragma unroll
        for (int mt = 0; mt < 2; ++mt)
          acc2[mt][nt] = mfma16(ah[mt][nh * 2 + (nt >> 1)], bi[nt], acc2[mt][nt]);

      float b2v[4];
#pragma unroll
      for (int nt = 0; nt < 4; ++nt) b2v[nt] = b2[nh * 64 + nt * 16 + lm];
#pragma unroll
      for (int mt = 0; mt < 2; ++mt) {
        if (!mv[mt]) continue;
#pragma unroll
        for (int r = 0; r < 4; ++r) {
          const int row = i0 + mt * 16 + quad * 4 + r;
#pragma unroll
          for (int nt = 0; nt < 4; ++nt) {
            const int col = nh * 64 + nt * 16 + lm;
            hb[(long)row * DN + col] = f2bf(acc2[mt][nt][r] + b2v[nt]);
          }
        }
      }
    }
  }
}

// ---------------------------------------------------------------------------
// Readout: segmented reduction over sorted batch, then MLP.
// ---------------------------------------------------------------------------
constexpr int GB = 512;

__global__ __launch_bounds__(128) void graph_acc(const unsigned short* __restrict__ hb,
                                                 const int* __restrict__ batch,
                                                 float* __restrict__ gacc,
                                                 float* __restrict__ gcnt) {
  const int c = threadIdx.x;
  const int per = (Nn + GB - 1) / GB;  // 98
  const int s0 = blockIdx.x * per;
  const int s1 = min(s0 + per, Nn);
  if (s0 >= s1) return;
  int cur = batch[s0];
  float acc = 0.f, cnt = 0.f;
  for (int i = s0; i < s1; ++i) {
    const int b = batch[i];
    if (b != cur) {
      atomicAdd(&gacc[cur * DN + c], acc);
      if (c == 0) atomicAdd(&gcnt[cur], cnt);
      acc = 0.f; cnt = 0.f; cur = b;
    }
    acc += bf2f(hb[(long)i * DN + c]);
    cnt += 1.f;
  }
  atomicAdd(&gacc[cur * DN + c], acc);
  if (c == 0) atomicAdd(&gcnt[cur], cnt);
}

__global__ __launch_bounds__(128) void readout(const float* __restrict__ gacc,
                                               const float* __restrict__ gcnt,
                                               const float* __restrict__ w1,
                                               const float* __restrict__ b1,
                                               const float* __restrict__ w2,
                                               const float* __restrict__ b2,
                                               float* __restrict__ out) {
  __shared__ float g[DN], t1[DN];
  const int b = blockIdx.x, c = threadIdx.x;
  const float inv = 1.0f / fmaxf(gcnt[b], 1.0f);
  g[c] = gacc[b * DN + c] * inv;
  __syncthreads();
  float acc = b1[c];
  for (int k = 0; k < DN; ++k) acc += g[k] * w1[k * DN + c];
  t1[c] = fmaxf(acc, 0.0f);
  __syncthreads();
  acc = b2[c];
  for (int k = 0; k < DN; ++k) acc += t1[k] * w2[k * DN + c];
  out[b * DN + c] = acc;
}

// ---------------------------------------------------------------------------
// Launch
// ---------------------------------------------------------------------------
extern "C" void kernel_launch(void* const* d_in, const int* in_sizes, int n_in,
                              void* d_out, int out_size, void* d_ws, size_t ws_size,
                              hipStream_t stream) {
  const float* x       = (const float*)d_in[0];
  const float* ea      = (const float*)d_in[1];
  const int*   ei      = (const int*)d_in[2];
  const int*   batch   = (const int*)d_in[3];
  const float* lin_x_w = (const float*)d_in[4];
  const float* lin_x_b = (const float*)d_in[5];
  const float* lin_e_w = (const float*)d_in[6];
  const float* lin_e_b = (const float*)d_in[7];
  const float* msg_w   = (const float*)d_in[8];
  const float* phie_w1 = (const float*)d_in[9];
  const float* phie_b1 = (const float*)d_in[10];
  const float* phie_w2 = (const float*)d_in[11];
  const float* phie_b2 = (const float*)d_in[12];
  const float* phiv_w1 = (const float*)d_in[13];
  const float* phiv_b1 = (const float*)d_in[14];
  const float* phiv_w2 = (const float*)d_in[15];
  const float* phiv_b2 = (const float*)d_in[16];
  const float* ro_w1   = (const float*)d_in[17];
  const float* ro_b1   = (const float*)d_in[18];
  const float* ro_w2   = (const float*)d_in[19];
  const float* ro_b2   = (const float*)d_in[20];

  const int* srcp = ei;
  const int* dstp = ei + Ne;

  // workspace layout (all region sizes multiples of 32B; zero-init block first)
  int*   deg_i  = (int*)d_ws;                    // Nn    (memset 0)
  float* gacc   = (float*)(deg_i + Nn);          // Bg*DN (memset 0)
  float* gcnt   = gacc + Bg * DN;                // Bg    (memset 0)
  float* invdeg = gcnt + Bg;                     // Nn
  int*   row_ptr= (int*)(invdeg + Nn);           // Nn+8
  int*   cursor = row_ptr + Nn + 8;              // Nn
  int*   bsum   = cursor + Nn;                   // 256
  int*   boff   = bsum + 256;                    // 256
  int*   perm   = boff + 256;                    // Ne
  int*   src_s  = perm + Ne;                     // Ne
  int*   dst_s  = src_s + Ne;                    // Ne
  unsigned short* hb   = (unsigned short*)(dst_s + Ne);  // Nn*DN
  unsigned short* eb   = hb + (long)Nn * DN;     // Ne*DE
  unsigned short* mb   = eb + (long)Ne * DE;     // Nn*DE
  unsigned short* weT  = mb + (long)Nn * DE;     // L*64*320
  unsigned short* ew2T = weT + (long)LAY * 64 * 320;
  unsigned short* vw1T = ew2T + (long)LAY * 64 * 64;
  unsigned short* vw2T = vw1T + (long)LAY * 64 * 192;

  hipMemsetAsync(deg_i, 0, sizeof(int) * Nn + sizeof(float) * (Bg * DN + Bg), stream);

  // CSR build (dst-sorted edge permutation)
  hist<<<(Ne + 255) / 256, 256, 0, stream>>>(dstp, deg_i);
  scan1<<<SB, 256, 0, stream>>>(deg_i, row_ptr, bsum);
  scan2<<<1, 256, 0, stream>>>(bsum, boff);
  scan3<<<SB, 256, 0, stream>>>(row_ptr, boff, deg_i, cursor, invdeg);
  scatter<<<(Ne + 255) / 256, 256, 0, stream>>>(srcp, dstp, cursor, perm, src_s, dst_s);

  prep_we<<<LAY * 64, 64, 0, stream>>>(phie_w1, msg_w, phie_w2, weT, ew2T);
  prep_wv<<<LAY * 128, 64, 0, stream>>>(phiv_w1, phiv_w2, vw1T, vw2T);
  enc_node<<<Nn, 128, 0, stream>>>(x, lin_x_w, lin_x_b, hb);
  enc_edge<<<Ne / 4, 256, 0, stream>>>(ea, perm, lin_e_w, lin_e_b, eb);

  const int eblocks = (Ne / 32 + 3) / 4;        // 1563
  const int vblocks = ((Nn + 31) / 32 + 3) / 4; // 391
  const int cblocks = (Nn + 3) / 4;             // 12500

  for (int l = 0; l < LAY; ++l) {
    edge_layer_mfma<<<eblocks, 256, 0, stream>>>(
        hb, eb, src_s, dst_s,
        weT + (long)l * 64 * 320, ew2T + (long)l * 64 * 64,
        phie_b1 + (long)l * HD, phie_b2 + (long)l * DE);
    csr_mean<<<cblocks, 256, 0, stream>>>(eb, row_ptr, invdeg, mb);
    node_layer_mfma<<<vblocks, 256, 0, stream>>>(
        hb, mb,
        vw1T + (long)l * 64 * 192, vw2T + (long)l * 128 * 64,
        phiv_b1 + (long)l * HD, phiv_b2 + (long)l * DN);
  }

  graph_acc<<<GB, 128, 0, stream>>>(hb, batch, gacc, gcnt);
  readout<<<Bg, 128, 0, stream>>>(gacc, gcnt, ro_w1, ro_b1, ro_w2, ro_b2,
                                  (float*)d_out);
}

// Round 6
// 762.970 us; speedup vs baseline: 11.1365x; 1.0968x over previous
//
#include <hip/hip_runtime.h>

// Problem constants
constexpr int Nn  = 50000;
constexpr int Ne  = 200000;
constexpr int Bg  = 64;
constexpr int DN  = 128;
constexpr int DE  = 64;
constexpr int HD  = 64;
constexpr int INN = 64;
constexpr int INE = 16;
constexpr int LAY = 6;
constexpr int SB  = 196;  // scan blocks: 196*256 >= Nn

typedef __attribute__((ext_vector_type(8))) short sh8;  // 8 bf16 = 4 VGPR
typedef __attribute__((ext_vector_type(4))) float f4;   // C/D frag

__device__ inline unsigned short f2bf(float x) {
  union { float f; unsigned u; } v; v.f = x;
  unsigned r = v.u + 0x7FFF + ((v.u >> 16) & 1);  // RNE
  return (unsigned short)(r >> 16);
}
__device__ inline float bf2f(unsigned short u) {
  union { unsigned u; float f; } v; v.u = ((unsigned)u) << 16; return v.f;
}
__device__ inline f4 mfma16(sh8 a, sh8 b, f4 c) {
  return __builtin_amdgcn_mfma_f32_16x16x32_bf16(a, b, c, 0, 0, 0);
}

// ---------------------------------------------------------------------------
// CSR build: histogram -> exclusive scan -> scatter (dst-sorted permutation)
// ---------------------------------------------------------------------------
__global__ void hist(const int* __restrict__ dst, int* __restrict__ deg) {
  const int j = blockIdx.x * blockDim.x + threadIdx.x;
  if (j < Ne) atomicAdd(&deg[dst[j]], 1);
}

__global__ __launch_bounds__(256) void scan1(const int* __restrict__ deg,
                                             int* __restrict__ rp,
                                             int* __restrict__ bsum) {
  __shared__ int s[256];
  const int t = threadIdx.x, i = blockIdx.x * 256 + t;
  const int v = (i < Nn) ? deg[i] : 0;
  s[t] = v; __syncthreads();
  for (int off = 1; off < 256; off <<= 1) {
    const int x = (t >= off) ? s[t - off] : 0;
    __syncthreads();
    s[t] += x;
    __syncthreads();
  }
  if (i < Nn) rp[i] = s[t] - v;  // intra-block exclusive
  if (t == 255) bsum[blockIdx.x] = s[255];
}

__global__ __launch_bounds__(256) void scan2(const int* __restrict__ bsum,
                                             int* __restrict__ boff) {
  __shared__ int s[256];
  const int t = threadIdx.x;
  const int v = (t < SB) ? bsum[t] : 0;
  s[t] = v; __syncthreads();
  for (int off = 1; off < 256; off <<= 1) {
    const int x = (t >= off) ? s[t - off] : 0;
    __syncthreads();
    s[t] += x;
    __syncthreads();
  }
  if (t < SB) boff[t] = s[t] - v;
}

__global__ __launch_bounds__(256) void scan3(int* __restrict__ rp,
                                             const int* __restrict__ boff,
                                             const int* __restrict__ deg,
                                             int* __restrict__ cursor,
                                             float* __restrict__ invdeg) {
  const int i = blockIdx.x * 256 + threadIdx.x;
  if (i < Nn) {
    const int r = rp[i] + boff[i >> 8];
    rp[i] = r;
    cursor[i] = r;
    invdeg[i] = 1.0f / fmaxf((float)deg[i], 1.0f);
  }
  if (i == 0) rp[Nn] = Ne;
}

__global__ void scatter(const int* __restrict__ src, const int* __restrict__ dst,
                        int* __restrict__ cursor, int* __restrict__ pos,
                        int* __restrict__ src_s, int* __restrict__ dst_s) {
  const int j = blockIdx.x * blockDim.x + threadIdx.x;
  if (j < Ne) {
    const int d = dst[j];
    const int p = atomicAdd(&cursor[d], 1);
    pos[j] = p;       // dst-sorted position of original edge j
    src_s[p] = src[j];
    dst_s[p] = d;
  }
}

// ---------------------------------------------------------------------------
// Weight prep.
// weT[l][n][k], k in [0,320): fused W1s (k<128), W1d (128..255), W1e (256..319)
// ---------------------------------------------------------------------------
__global__ __launch_bounds__(64) void prep_we(const float* __restrict__ ew1,
                                              const float* __restrict__ mw,
                                              const float* __restrict__ ew2,
                                              unsigned short* __restrict__ weT,
                                              unsigned short* __restrict__ ew2T) {
  const int l = blockIdx.x >> 6, n = blockIdx.x & 63, t = threadIdx.x;
  const float* E1 = ew1 + (long)l * 320 * 64;
  const float* MW = mw + (long)l * 128 * 64;
  const float* E2 = ew2 + (long)l * 64 * 64;
  unsigned short* W = weT + (long)l * 64 * 320 + (long)n * 320;
  __shared__ float c[64];
  c[t] = E1[(256 + t) * 64 + n];
  __syncthreads();
  for (int k = t; k < 128; k += 64) {
    float s = E1[k * 64 + n];
    for (int j = 0; j < 64; ++j) s += MW[k * 64 + j] * c[j];
    W[k] = f2bf(s);
  }
  for (int k = 128 + t; k < 320; k += 64) W[k] = f2bf(E1[k * 64 + n]);
  ew2T[(long)l * 64 * 64 + n * 64 + t] = f2bf(E2[t * 64 + n]);
}

__global__ __launch_bounds__(64) void prep_wv(const float* __restrict__ vw1,
                                              const float* __restrict__ vw2,
                                              unsigned short* __restrict__ vw1T,
                                              unsigned short* __restrict__ vw2T) {
  const int l = blockIdx.x >> 7, n = blockIdx.x & 127, t = threadIdx.x;
  vw2T[(long)l * 128 * 64 + n * 64 + t] = f2bf(vw2[(long)l * 64 * 128 + t * 128 + n]);
  if (n < 64) {
    for (int k = t; k < 192; k += 64)
      vw1T[(long)l * 64 * 192 + n * 192 + k] = f2bf(vw1[(long)l * 192 * 64 + k * 64 + n]);
  }
}

// wxT[n][k]: lin_x_w [64][128] -> transposed bf16 [128][64]
__global__ __launch_bounds__(64) void prep_wx(const float* __restrict__ w,
                                              unsigned short* __restrict__ wxT) {
  const int n = blockIdx.x, t = threadIdx.x;
  wxT[n * INN + t] = f2bf(w[t * DN + n]);
}

// ---------------------------------------------------------------------------
// Node encoder (MFMA): h = x @ lin_x_w + b. Wave = 32 nodes, K=64, N=128.
// x converted fp32->bf16 in-register.
// ---------------------------------------------------------------------------
__global__ __launch_bounds__(256) void enc_node_mfma(
    const float* __restrict__ x,
    const unsigned short* __restrict__ wxT,  // [128][64]
    const float* __restrict__ b,
    unsigned short* __restrict__ hb) {
  const int lane = threadIdx.x & 63;
  const int wv   = threadIdx.x >> 6;
  const int quad = lane >> 4;
  const int lm   = lane & 15;
  const int wid  = blockIdx.x * 4 + wv;
  const int ntiles = (Nn + 31) / 32;  // 1563
  if (wid >= ntiles) return;
  const int i0 = wid * 32;

  bool mv[2];
#pragma unroll
  for (int mt = 0; mt < 2; ++mt) mv[mt] = (i0 + mt * 16) < Nn;

  f4 acc[2][8];
#pragma unroll
  for (int mt = 0; mt < 2; ++mt)
#pragma unroll
    for (int nt = 0; nt < 8; ++nt) acc[mt][nt] = f4{0.f, 0.f, 0.f, 0.f};

#pragma unroll
  for (int ks = 0; ks < 2; ++ks) {
    const int kb = ks * 32 + quad * 8;
    sh8 a[2], bfr[8];
#pragma unroll
    for (int mt = 0; mt < 2; ++mt) {
      const int row = i0 + mt * 16 + lm;
      if (mv[mt] && row < Nn) {
        const float* xp = x + (long)row * INN + kb;
        const float4 v0 = *(const float4*)xp;
        const float4 v1 = *(const float4*)(xp + 4);
        a[mt][0] = (short)f2bf(v0.x); a[mt][1] = (short)f2bf(v0.y);
        a[mt][2] = (short)f2bf(v0.z); a[mt][3] = (short)f2bf(v0.w);
        a[mt][4] = (short)f2bf(v1.x); a[mt][5] = (short)f2bf(v1.y);
        a[mt][6] = (short)f2bf(v1.z); a[mt][7] = (short)f2bf(v1.w);
      } else a[mt] = (sh8)0;
    }
#pragma unroll
    for (int nt = 0; nt < 8; ++nt)
      bfr[nt] = *(const sh8*)(wxT + (nt * 16 + lm) * INN + kb);
#pragma unroll
    for (int mt = 0; mt < 2; ++mt)
#pragma unroll
      for (int nt = 0; nt < 8; ++nt)
        acc[mt][nt] = mfma16(a[mt], bfr[nt], acc[mt][nt]);
  }
  float bv[8];
#pragma unroll
  for (int nt = 0; nt < 8; ++nt) bv[nt] = b[nt * 16 + lm];
#pragma unroll
  for (int mt = 0; mt < 2; ++mt) {
    if (!mv[mt]) continue;
#pragma unroll
    for (int r = 0; r < 4; ++r) {
      const int row = i0 + mt * 16 + quad * 4 + r;
      if (row >= Nn) continue;
#pragma unroll
      for (int nt = 0; nt < 8; ++nt)
        hb[(long)row * DN + nt * 16 + lm] = f2bf(acc[mt][nt][r] + bv[nt]);
    }
  }
}

// ---------------------------------------------------------------------------
// Edge encoder: sequential coalesced read of ea, scatter-write to dst-sorted eb.
// Block = 64 edges staged in LDS; weight column in 16 VGPRs per lane.
// ---------------------------------------------------------------------------
__global__ __launch_bounds__(256) void enc_edge(const float* __restrict__ ea,
                                                const int* __restrict__ pos,
                                                const float* __restrict__ w,
                                                const float* __restrict__ b,
                                                unsigned short* __restrict__ eb) {
  __shared__ float S[64 * INE];
  const int t = threadIdx.x;
  const int j0 = blockIdx.x * 64;  // Ne/64 = 3125 blocks
  *(float4*)&S[t * 4] = *(const float4*)&ea[(long)j0 * INE + t * 4];
  __syncthreads();
  const int lane = t & 63, wv = t >> 6;
  float wreg[INE];
#pragma unroll
  for (int k = 0; k < INE; ++k) wreg[k] = w[k * DE + lane];
  const float bias = b[lane];
#pragma unroll
  for (int el = 0; el < 16; ++el) {
    const int e = wv * 16 + el;
    float acc = bias;
#pragma unroll
    for (int k = 0; k < INE; ++k) acc += S[e * INE + k] * wreg[k];
    eb[(long)pos[j0 + e] * DE + lane] = f2bf(acc);
  }
}

// ---------------------------------------------------------------------------
// Edge layer (MFMA). Wave = 32 edges (2 M-tiles), dst-sorted order.
// A = [hb[src]|hb[dst]|eb], K=320. u = relu(A@W1+b1);
// e' = [u|e] @ [W2; I] + b2 (residual fused as identity MFMA). Writes eb only.
// ---------------------------------------------------------------------------
constexpr int UP = 72;  // Us pitch (bf16): 144B rows

__global__ __launch_bounds__(256) void edge_layer_mfma(
    const unsigned short* __restrict__ hb,
    unsigned short* __restrict__ eb,
    const int* __restrict__ src_s, const int* __restrict__ dst_s,
    const unsigned short* __restrict__ weT,   // [64][320]
    const unsigned short* __restrict__ ew2T,  // [64][64]
    const float* __restrict__ b1, const float* __restrict__ b2) {
  __shared__ unsigned short Us[4][32 * UP];
  const int lane = threadIdx.x & 63;
  const int wv   = threadIdx.x >> 6;
  const int quad = lane >> 4;
  const int lm   = lane & 15;
  const int wid  = blockIdx.x * 4 + wv;
  const int ntiles = Ne / 32;  // 6250
  const bool act = wid < ntiles;
  const int j0 = wid * 32;
  unsigned short* us = Us[wv];

  sh8 ae[2][2];  // saved eb A-frags (K 256..319) for the residual identity

  if (act) {
    int aoff_s[2], aoff_d[2], aoff_e[2];
#pragma unroll
    for (int mt = 0; mt < 2; ++mt) {
      const int j = j0 + mt * 16 + lm;
      aoff_s[mt] = src_s[j] * DN;
      aoff_d[mt] = dst_s[j] * DN;
      aoff_e[mt] = j * DE;
    }
    f4 acc[2][4];
#pragma unroll
    for (int mt = 0; mt < 2; ++mt)
#pragma unroll
      for (int nt = 0; nt < 4; ++nt) acc[mt][nt] = f4{0.f, 0.f, 0.f, 0.f};

#pragma unroll
    for (int ks = 0; ks < 10; ++ks) {
      const int kb = ks * 32 + quad * 8;
      sh8 a[2], b[4];
#pragma unroll
      for (int mt = 0; mt < 2; ++mt) {
        const unsigned short* ap;
        if (ks < 4)      ap = hb + aoff_s[mt] + kb;
        else if (ks < 8) ap = hb + aoff_d[mt] + (kb - 128);
        else             ap = eb + aoff_e[mt] + (kb - 256);
        a[mt] = *(const sh8*)ap;
        if (ks >= 8) ae[mt][ks - 8] = a[mt];
      }
#pragma unroll
      for (int nt = 0; nt < 4; ++nt)
        b[nt] = *(const sh8*)(weT + (nt * 16 + lm) * 320 + kb);
#pragma unroll
      for (int mt = 0; mt < 2; ++mt)
#pragma unroll
        for (int nt = 0; nt < 4; ++nt)
          acc[mt][nt] = mfma16(a[mt], b[nt], acc[mt][nt]);
    }
    float b1v[4];
#pragma unroll
    for (int nt = 0; nt < 4; ++nt) b1v[nt] = b1[nt * 16 + lm];
#pragma unroll
    for (int mt = 0; mt < 2; ++mt)
#pragma unroll
      for (int nt = 0; nt < 4; ++nt)
#pragma unroll
        for (int r = 0; r < 4; ++r) {
          const int row = mt * 16 + quad * 4 + r;
          const int col = nt * 16 + lm;
          us[row * UP + col] = f2bf(fmaxf(acc[mt][nt][r] + b1v[nt], 0.f));
        }
  }
  __syncthreads();
  if (act) {
    f4 acc2[2][4];
#pragma unroll
    for (int mt = 0; mt < 2; ++mt)
#pragma unroll
      for (int nt = 0; nt < 4; ++nt) acc2[mt][nt] = f4{0.f, 0.f, 0.f, 0.f};
#pragma unroll
    for (int ks = 0; ks < 2; ++ks) {
      const int kb = ks * 32 + quad * 8;
      sh8 a[2], b[4];
#pragma unroll
      for (int mt = 0; mt < 2; ++mt)
        a[mt] = *(const sh8*)&us[(mt * 16 + lm) * UP + kb];
#pragma unroll
      for (int nt = 0; nt < 4; ++nt)
        b[nt] = *(const sh8*)(ew2T + (nt * 16 + lm) * 64 + kb);
#pragma unroll
      for (int mt = 0; mt < 2; ++mt)
#pragma unroll
        for (int nt = 0; nt < 4; ++nt)
          acc2[mt][nt] = mfma16(a[mt], b[nt], acc2[mt][nt]);
    }
    // residual: acc2 += Eb_tile @ I (one MFMA per nt)
#pragma unroll
    for (int nt = 0; nt < 4; ++nt) {
      const int d = nt * 16 + lm - (nt >> 1) * 32 - quad * 8;
      sh8 bi;
#pragma unroll
      for (int jj = 0; jj < 8; ++jj) bi[jj] = (d == jj) ? (short)0x3F80 : (short)0;
#pragma unroll
      for (int mt = 0; mt < 2; ++mt)
        acc2[mt][nt] = mfma16(ae[mt][nt >> 1], bi, acc2[mt][nt]);
    }
    float b2v[4];
#pragma unroll
    for (int nt = 0; nt < 4; ++nt) b2v[nt] = b2[nt * 16 + lm];
#pragma unroll
    for (int mt = 0; mt < 2; ++mt)
#pragma unroll
      for (int r = 0; r < 4; ++r) {
        const int j = j0 + mt * 16 + quad * 4 + r;
#pragma unroll
        for (int nt = 0; nt < 4; ++nt) {
          const int col = nt * 16 + lm;
          eb[(long)j * DE + col] = f2bf(acc2[mt][nt][r] + b2v[nt]);
        }
      }
  }
}

// ---------------------------------------------------------------------------
// CSR segmented mean: mb[i] = bf16(invdeg[i] * sum_{j in rp[i]..rp[i+1]} eb[j])
// ---------------------------------------------------------------------------
__global__ __launch_bounds__(256) void csr_mean(const unsigned short* __restrict__ eb,
                                                const int* __restrict__ rp,
                                                const float* __restrict__ invdeg,
                                                unsigned short* __restrict__ mb) {
  const int i = blockIdx.x * 4 + (threadIdx.x >> 6);
  const int c = threadIdx.x & 63;
  if (i >= Nn) return;
  const int s = rp[i], t = rp[i + 1];
  float sum = 0.f;
  for (int j = s; j < t; ++j) sum += bf2f(eb[(long)j * DE + c]);
  mb[(long)i * DE + c] = f2bf(sum * invdeg[i]);
}

// ---------------------------------------------------------------------------
// Node layer (MFMA). Wave = 32 nodes (2 M-tiles). A = [hb | mb], K=192.
// u = relu(A @ vw1 + b1); h' = [u | h] @ [vw2; I] + b2 (residual fused).
// ---------------------------------------------------------------------------
__global__ __launch_bounds__(256) void node_layer_mfma(
    unsigned short* __restrict__ hb,
    const unsigned short* __restrict__ mb,
    const unsigned short* __restrict__ vw1T,  // [64][192]
    const unsigned short* __restrict__ vw2T,  // [128][64]
    const float* __restrict__ b1, const float* __restrict__ b2) {
  __shared__ unsigned short Us[4][32 * UP];
  const int lane = threadIdx.x & 63;
  const int wv   = threadIdx.x >> 6;
  const int quad = lane >> 4;
  const int lm   = lane & 15;
  const int wid  = blockIdx.x * 4 + wv;
  const int ntiles = (Nn + 31) / 32;  // 1563
  const bool act = wid < ntiles;
  const int i0 = wid * 32;
  unsigned short* us = Us[wv];

  bool mv[2];
#pragma unroll
  for (int mt = 0; mt < 2; ++mt) mv[mt] = act && (i0 + mt * 16) < Nn;

  sh8 ah[2][4];  // saved hb A-frags (K 0..127) for the residual identity

  if (act) {
    f4 acc[2][4];
#pragma unroll
    for (int mt = 0; mt < 2; ++mt)
#pragma unroll
      for (int nt = 0; nt < 4; ++nt) acc[mt][nt] = f4{0.f, 0.f, 0.f, 0.f};
#pragma unroll
    for (int ks = 0; ks < 6; ++ks) {
      const int kb = ks * 32 + quad * 8;
      sh8 a[2], b[4];
#pragma unroll
      for (int mt = 0; mt < 2; ++mt) {
        const int row = i0 + mt * 16 + lm;
        if (mv[mt]) {
          if (ks < 4) a[mt] = *(const sh8*)(hb + (long)row * DN + kb);
          else        a[mt] = *(const sh8*)(mb + (long)row * DE + (kb - 128));
        } else a[mt] = (sh8)0;
        if (ks < 4) ah[mt][ks] = a[mt];
      }
#pragma unroll
      for (int nt = 0; nt < 4; ++nt)
        b[nt] = *(const sh8*)(vw1T + (nt * 16 + lm) * 192 + kb);
#pragma unroll
      for (int mt = 0; mt < 2; ++mt)
#pragma unroll
        for (int nt = 0; nt < 4; ++nt)
          acc[mt][nt] = mfma16(a[mt], b[nt], acc[mt][nt]);
    }
    float b1v[4];
#pragma unroll
    for (int nt = 0; nt < 4; ++nt) b1v[nt] = b1[nt * 16 + lm];
#pragma unroll
    for (int mt = 0; mt < 2; ++mt)
#pragma unroll
      for (int nt = 0; nt < 4; ++nt)
#pragma unroll
        for (int r = 0; r < 4; ++r) {
          const int row = mt * 16 + quad * 4 + r;
          const int col = nt * 16 + lm;
          us[row * UP + col] = f2bf(fmaxf(acc[mt][nt][r] + b1v[nt], 0.f));
        }
  }
  __syncthreads();
  if (act) {
    sh8 bi[4];
#pragma unroll
    for (int nt = 0; nt < 4; ++nt) {
      const int d = nt * 16 + lm - (nt >> 1) * 32 - quad * 8;
#pragma unroll
      for (int jj = 0; jj < 8; ++jj) bi[nt][jj] = (d == jj) ? (short)0x3F80 : (short)0;
    }
#pragma unroll
    for (int nh = 0; nh < 2; ++nh) {
      f4 acc2[2][4];
#pragma unroll
      for (int mt = 0; mt < 2; ++mt)
#pragma unroll
        for (int nt = 0; nt < 4; ++nt) acc2[mt][nt] = f4{0.f, 0.f, 0.f, 0.f};
#pragma unroll
      for (int ks = 0; ks < 2; ++ks) {
        const int kb = ks * 32 + quad * 8;
        sh8 a[2], b[4];
#pragma unroll
        for (int mt = 0; mt < 2; ++mt)
          a[mt] = *(const sh8*)&us[(mt * 16 + lm) * UP + kb];
#pragma unroll
        for (int nt = 0; nt < 4; ++nt)
          b[nt] = *(const sh8*)(vw2T + (nh * 64 + nt * 16 + lm) * 64 + kb);
#pragma unroll
        for (int mt = 0; mt < 2; ++mt)
#pragma unroll
          for (int nt = 0; nt < 4; ++nt)
            acc2[mt][nt] = mfma16(a[mt], b[nt], acc2[mt][nt]);
      }
#pragma unroll
      for (int nt = 0; nt < 4; ++nt)
#pragma unroll
        for (int mt = 0; mt < 2; ++mt)
          acc2[mt][nt] = mfma16(ah[mt][nh * 2 + (nt >> 1)], bi[nt], acc2[mt][nt]);

      float b2v[4];
#pragma unroll
      for (int nt = 0; nt < 4; ++nt) b2v[nt] = b2[nh * 64 + nt * 16 + lm];
#pragma unroll
      for (int mt = 0; mt < 2; ++mt) {
        if (!mv[mt]) continue;
#pragma unroll
        for (int r = 0; r < 4; ++r) {
          const int row = i0 + mt * 16 + quad * 4 + r;
#pragma unroll
          for (int nt = 0; nt < 4; ++nt) {
            const int col = nh * 64 + nt * 16 + lm;
            hb[(long)row * DN + col] = f2bf(acc2[mt][nt][r] + b2v[nt]);
          }
        }
      }
    }
  }
}

// ---------------------------------------------------------------------------
// Readout: segmented reduction over sorted batch, then MLP.
// ---------------------------------------------------------------------------
constexpr int GB = 512;

__global__ __launch_bounds__(128) void graph_acc(const unsigned short* __restrict__ hb,
                                                 const int* __restrict__ batch,
                                                 float* __restrict__ gacc,
                                                 float* __restrict__ gcnt) {
  const int c = threadIdx.x;
  const int per = (Nn + GB - 1) / GB;  // 98
  const int s0 = blockIdx.x * per;
  const int s1 = min(s0 + per, Nn);
  if (s0 >= s1) return;
  int cur = batch[s0];
  float acc = 0.f, cnt = 0.f;
  for (int i = s0; i < s1; ++i) {
    const int b = batch[i];
    if (b != cur) {
      atomicAdd(&gacc[cur * DN + c], acc);
      if (c == 0) atomicAdd(&gcnt[cur], cnt);
      acc = 0.f; cnt = 0.f; cur = b;
    }
    acc += bf2f(hb[(long)i * DN + c]);
    cnt += 1.f;
  }
  atomicAdd(&gacc[cur * DN + c], acc);
  if (c == 0) atomicAdd(&gcnt[cur], cnt);
}

__global__ __launch_bounds__(128) void readout(const float* __restrict__ gacc,
                                               const float* __restrict__ gcnt,
                                               const float* __restrict__ w1,
                                               const float* __restrict__ b1,
                                               const float* __restrict__ w2,
                                               const float* __restrict__ b2,
                                               float* __restrict__ out) {
  __shared__ float g[DN], t1[DN];
  const int b = blockIdx.x, c = threadIdx.x;
  const float inv = 1.0f / fmaxf(gcnt[b], 1.0f);
  g[c] = gacc[b * DN + c] * inv;
  __syncthreads();
  float acc = b1[c];
  for (int k = 0; k < DN; ++k) acc += g[k] * w1[k * DN + c];
  t1[c] = fmaxf(acc, 0.0f);
  __syncthreads();
  acc = b2[c];
  for (int k = 0; k < DN; ++k) acc += t1[k] * w2[k * DN + c];
  out[b * DN + c] = acc;
}

// ---------------------------------------------------------------------------
// Launch
// ---------------------------------------------------------------------------
extern "C" void kernel_launch(void* const* d_in, const int* in_sizes, int n_in,
                              void* d_out, int out_size, void* d_ws, size_t ws_size,
                              hipStream_t stream) {
  const float* x       = (const float*)d_in[0];
  const float* ea      = (const float*)d_in[1];
  const int*   ei      = (const int*)d_in[2];
  const int*   batch   = (const int*)d_in[3];
  const float* lin_x_w = (const float*)d_in[4];
  const float* lin_x_b = (const float*)d_in[5];
  const float* lin_e_w = (const float*)d_in[6];
  const float* lin_e_b = (const float*)d_in[7];
  const float* msg_w   = (const float*)d_in[8];
  const float* phie_w1 = (const float*)d_in[9];
  const float* phie_b1 = (const float*)d_in[10];
  const float* phie_w2 = (const float*)d_in[11];
  const float* phie_b2 = (const float*)d_in[12];
  const float* phiv_w1 = (const float*)d_in[13];
  const float* phiv_b1 = (const float*)d_in[14];
  const float* phiv_w2 = (const float*)d_in[15];
  const float* phiv_b2 = (const float*)d_in[16];
  const float* ro_w1   = (const float*)d_in[17];
  const float* ro_b1   = (const float*)d_in[18];
  const float* ro_w2   = (const float*)d_in[19];
  const float* ro_b2   = (const float*)d_in[20];

  const int* srcp = ei;
  const int* dstp = ei + Ne;

  // workspace layout
  int*   deg_i  = (int*)d_ws;                    // Nn    (memset 0)
  float* gacc   = (float*)(deg_i + Nn);          // Bg*DN (memset 0)
  float* gcnt   = gacc + Bg * DN;                // Bg    (memset 0)
  float* invdeg = gcnt + Bg;                     // Nn
  int*   row_ptr= (int*)(invdeg + Nn);           // Nn+8
  int*   cursor = row_ptr + Nn + 8;              // Nn
  int*   bsum   = cursor + Nn;                   // 256
  int*   boff   = bsum + 256;                    // 256
  int*   pos    = boff + 256;                    // Ne
  int*   src_s  = pos + Ne;                      // Ne
  int*   dst_s  = src_s + Ne;                    // Ne
  unsigned short* hb   = (unsigned short*)(dst_s + Ne);  // Nn*DN
  unsigned short* eb   = hb + (long)Nn * DN;     // Ne*DE
  unsigned short* mb   = eb + (long)Ne * DE;     // Nn*DE
  unsigned short* weT  = mb + (long)Nn * DE;     // L*64*320
  unsigned short* ew2T = weT + (long)LAY * 64 * 320;
  unsigned short* vw1T = ew2T + (long)LAY * 64 * 64;
  unsigned short* vw2T = vw1T + (long)LAY * 64 * 192;
  unsigned short* wxT  = vw2T + (long)LAY * 128 * 64;  // 128*64

  hipMemsetAsync(deg_i, 0, sizeof(int) * Nn + sizeof(float) * (Bg * DN + Bg), stream);

  // CSR build (dst-sorted edge permutation)
  hist<<<(Ne + 255) / 256, 256, 0, stream>>>(dstp, deg_i);
  scan1<<<SB, 256, 0, stream>>>(deg_i, row_ptr, bsum);
  scan2<<<1, 256, 0, stream>>>(bsum, boff);
  scan3<<<SB, 256, 0, stream>>>(row_ptr, boff, deg_i, cursor, invdeg);
  scatter<<<(Ne + 255) / 256, 256, 0, stream>>>(srcp, dstp, cursor, pos, src_s, dst_s);

  prep_we<<<LAY * 64, 64, 0, stream>>>(phie_w1, msg_w, phie_w2, weT, ew2T);
  prep_wv<<<LAY * 128, 64, 0, stream>>>(phiv_w1, phiv_w2, vw1T, vw2T);
  prep_wx<<<DN, 64, 0, stream>>>(lin_x_w, wxT);

  const int vblocks = ((Nn + 31) / 32 + 3) / 4; // 391
  enc_node_mfma<<<vblocks, 256, 0, stream>>>(x, wxT, lin_x_b, hb);
  enc_edge<<<Ne / 64, 256, 0, stream>>>(ea, pos, lin_e_w, lin_e_b, eb);

  const int eblocks = (Ne / 32 + 3) / 4;        // 1563
  const int cblocks = (Nn + 3) / 4;             // 12500

  for (int l = 0; l < LAY; ++l) {
    edge_layer_mfma<<<eblocks, 256, 0, stream>>>(
        hb, eb, src_s, dst_s,
        weT + (long)l * 64 * 320, ew2T + (long)l * 64 * 64,
        phie_b1 + (long)l * HD, phie_b2 + (long)l * DE);
    csr_mean<<<cblocks, 256, 0, stream>>>(eb, row_ptr, invdeg, mb);
    node_layer_mfma<<<vblocks, 256, 0, stream>>>(
        hb, mb,
        vw1T + (long)l * 64 * 192, vw2T + (long)l * 128 * 64,
        phiv_b1 + (long)l * HD, phiv_b2 + (long)l * DN);
  }

  graph_acc<<<GB, 128, 0, stream>>>(hb, batch, gacc, gcnt);
  readout<<<Bg, 128, 0, stream>>>(gacc, gcnt, ro_w1, ro_b1, ro_w2, ro_b2,
                                  (float*)d_out);
}